// Round 7
// baseline (400.547 us; speedup 1.0000x reference)
//
#include <hip/hip_runtime.h>

// Problem constants (match reference setup_inputs)
constexpr int CN0 = 1000000;   // x rows
constexpr int CN1 = 300000;    // stem conv output rows
constexpr int CN2 = 80000;     // pooled rows
constexpr int CN3 = 30000;     // downsampled rows
constexpr float BN_EPS = 1e-5f;

typedef __attribute__((ext_vector_type(8))) short bf16x8;
typedef __attribute__((ext_vector_type(4))) float f32x4;

union FragU { uint4 u; bf16x8 b; };

__device__ __forceinline__ float2 bn_ab(float s, float q, float invn, float gamma, float beta) {
  float m = s * invn;
  float v = fmaf(q, invn, -m * m);
  float rstd = rsqrtf(v + BN_EPS);
  float a = gamma * rstd;
  float b = beta - m * a;
  return make_float2(a, b);
}

// round-to-nearest-even fp32 -> bf16
__device__ __forceinline__ unsigned short f2bf(float f) {
  unsigned u = __float_as_uint(f);
  u += 0x7FFFu + ((u >> 16) & 1u);
  return (unsigned short)(u >> 16);
}

// LDS-only barrier: waits ds ops, does NOT drain vmcnt -> prefetched global
// loads stay in flight across the barrier.
__device__ __forceinline__ void sync_lds() {
  asm volatile("s_waitcnt lgkmcnt(0)" ::: "memory");
  __builtin_amdgcn_s_barrier();
  asm volatile("" ::: "memory");
}

// ---------------------------------------------------------------------------
// Prep: x (f32 [1M][4]) -> xbf (bf16 [1M][4])
// ---------------------------------------------------------------------------
__global__ __launch_bounds__(256) void k_prep_x(
    const float* __restrict__ x, unsigned int* __restrict__ xbf) {
  int i = blockIdx.x * 256 + threadIdx.x;
  if (i >= CN0) return;
  float4 v = *(const float4*)(x + i * 4);
  uint2 p;
  p.x = (unsigned)f2bf(v.x) | ((unsigned)f2bf(v.y) << 16);
  p.y = (unsigned)f2bf(v.z) | ((unsigned)f2bf(v.w) << 16);
  *(uint2*)(xbf + i * 2) = p;
}

// ---------------------------------------------------------------------------
// Prep: W_stem [27][4][64] f32 -> per-lane MFMA B fragments (r6 layout):
// Wf[((ks*4+nf)*64 + lane)*8 + e] = W[k][d], k=ks*32+(lane>>4)*8+e (pad>=108),
// d = nf*16+(lane&15).
// ---------------------------------------------------------------------------
__global__ __launch_bounds__(256) void k_prep_stem(
    const float* __restrict__ W, unsigned short* __restrict__ Wt) {
  int f = blockIdx.x * 256 + threadIdx.x;  // 8192
  if (f >= 8192) return;
  int e = f & 7, lane = (f >> 3) & 63, nf = (f >> 9) & 3, ks = f >> 11;
  int k = ks * 32 + (lane >> 4) * 8 + e;
  int d = nf * 16 + (lane & 15);
  Wt[f] = (k < 108) ? f2bf(W[k * 64 + d]) : (unsigned short)0;
}

// ---------------------------------------------------------------------------
// Prep: dual weights [W1|Wd] -> per-lane fragment layout
// Wf[tap][ks1][nfg(0..7)][lane][e]: cin=ks1*32+(lane>>4)*8+e, d=nfg*16+(lane&15)
// ---------------------------------------------------------------------------
__global__ __launch_bounds__(256) void k_prep_dual(
    const float* __restrict__ W1, const float* __restrict__ Wd,
    unsigned short* __restrict__ Wf) {
  int f = blockIdx.x * 256 + threadIdx.x;  // 27*8192 = 221184
  if (f >= 27 * 8192) return;
  int tap = f >> 13, r = f & 8191;
  int ks1 = (r >> 12) & 1, nfg = (r >> 9) & 7, lane = (r >> 3) & 63, e = r & 7;
  int cin = ks1 * 32 + (lane >> 4) * 8 + e;
  int d = nfg * 16 + (lane & 15);
  float v = (d < 64) ? W1[(tap * 64 + cin) * 64 + d]
                     : Wd[(tap * 64 + cin) * 64 + (d - 64)];
  Wf[f] = f2bf(v);
}

__global__ __launch_bounds__(256) void k_prep_res(
    const float* __restrict__ W2, unsigned short* __restrict__ Wf) {
  int f = blockIdx.x * 256 + threadIdx.x;  // 27*4096 = 110592
  if (f >= 27 * 4096) return;
  int tap = f >> 12, r = f & 4095;
  int ks1 = (r >> 11) & 1, nfg = (r >> 9) & 3, lane = (r >> 3) & 63, e = r & 7;
  int cin = ks1 * 32 + (lane >> 4) * 8 + e;
  int d = nfg * 16 + (lane & 15);
  Wf[f] = f2bf(W2[(tap * 64 + cin) * 64 + d]);
}

// ---------------------------------------------------------------------------
// Stem conv via MFMA, register-direct gather, T=2 tiles/block with FULL
// prologue prefetch: all 16 gathers of both tiles in flight across one
// lgkm-only barrier. 2344 blocks for max resident waves.
// ---------------------------------------------------------------------------
__global__ __launch_bounds__(256) void k_stem_mfma(
    const unsigned short* __restrict__ xbf, const int* __restrict__ neigh,
    const unsigned short* __restrict__ Wf, unsigned short* __restrict__ y1,
    float* __restrict__ stats) {
  __shared__ __align__(16) uint4 Bb[1024];  // 16 KB B fragments
  const int tid = threadIdx.x;
  const int lane = tid & 63;
  const int wv = tid >> 6;
  const int l15 = lane & 15, lq = lane >> 4;
  const int g0 = blockIdx.x * 2;

  // B global loads first
  uint4 wreg[4];
  {
    const uint4* Ws = (const uint4*)Wf;
#pragma unroll
    for (int j = 0; j < 4; ++j) wreg[j] = Ws[tid + j * 256];
  }

  int idx0[8], idx1[8];
#define LDIDX(g, dst)                                                      \
  {                                                                        \
    int node_ = (g)*64 + wv * 16 + l15;                                    \
    bool rowok_ = node_ < CN1;                                             \
    const int* nb_ = neigh + node_ * 27;                                   \
    _Pragma("unroll") for (int ks_ = 0; ks_ < 4; ++ks_) {                  \
      int tap0_ = ks_ * 8 + lq * 2;                                        \
      dst[ks_ * 2] = (rowok_ && tap0_ < 27) ? nb_[tap0_] : -1;             \
      dst[ks_ * 2 + 1] = (rowok_ && tap0_ + 1 < 27) ? nb_[tap0_ + 1] : -1; \
    }                                                                      \
  }
#define GATHER(idx, frag)                                                  \
  {                                                                        \
    _Pragma("unroll") for (int ks_ = 0; ks_ < 4; ++ks_) {                  \
      uint2 v0_ = {0u, 0u}, v1_ = {0u, 0u};                                \
      if (idx[ks_ * 2] >= 0)                                               \
        v0_ = *(const uint2*)(xbf + idx[ks_ * 2] * 4);                     \
      if (idx[ks_ * 2 + 1] >= 0)                                           \
        v1_ = *(const uint2*)(xbf + idx[ks_ * 2 + 1] * 4);                 \
      frag[ks_].u.x = v0_.x; frag[ks_].u.y = v0_.y;                        \
      frag[ks_].u.z = v1_.x; frag[ks_].u.w = v1_.y;                        \
    }                                                                      \
  }

  LDIDX(g0 + 0, idx0);
  LDIDX(g0 + 1, idx1);
  FragU fA[4], fB[4];
  GATHER(idx0, fA);   // both tiles' gathers in flight together
  GATHER(idx1, fB);

#pragma unroll
  for (int j = 0; j < 4; ++j) Bb[tid + j * 256] = wreg[j];
  sync_lds();  // gathers stay in flight

  float sacc[4] = {0.f, 0.f, 0.f, 0.f};
  float qacc[4] = {0.f, 0.f, 0.f, 0.f};

#pragma unroll
  for (int t = 0; t < 2; ++t) {
    FragU* cur = t ? fB : fA;
    f32x4 acc[4] = {};
#pragma unroll
    for (int ks = 0; ks < 4; ++ks) {
#pragma unroll
      for (int nf = 0; nf < 4; ++nf) {
        bf16x8 b = *(const bf16x8*)&Bb[(ks * 4 + nf) * 64 + lane];
        acc[nf] = __builtin_amdgcn_mfma_f32_16x16x32_bf16(cur[ks].b, b,
                                                          acc[nf], 0, 0, 0);
      }
    }
    int n0 = (g0 + t) * 64 + wv * 16;
#pragma unroll
    for (int nf = 0; nf < 4; ++nf) {
      int c = nf * 16 + l15;
#pragma unroll
      for (int r = 0; r < 4; ++r) {
        int row = n0 + lq * 4 + r;
        float v = acc[nf][r];
        if (row < CN1) y1[row * 64 + c] = f2bf(v);
        sacc[nf] += v;
        qacc[nf] = fmaf(v, v, qacc[nf]);
      }
    }
  }
#undef LDIDX
#undef GATHER

  // cross-wave stats reduction (reuse Bb as scratch)
  sync_lds();
  float* S = (float*)Bb;
#pragma unroll
  for (int nf = 0; nf < 4; ++nf) {
    float s = sacc[nf], q = qacc[nf];
    s += __shfl_xor(s, 16); s += __shfl_xor(s, 32);
    q += __shfl_xor(q, 16); q += __shfl_xor(q, 32);
    if (lane < 16) {
      S[wv * 64 + nf * 16 + lane] = s;
      S[256 + wv * 64 + nf * 16 + lane] = q;
    }
  }
  __syncthreads();
  if (tid < 64) {
    float s = S[tid] + S[64 + tid] + S[128 + tid] + S[192 + tid];
    float q = S[256 + tid] + S[320 + tid] + S[384 + tid] + S[448 + tid];
    atomicAdd(&stats[tid], s);
    atomicAdd(&stats[64 + tid], q);
  }
}

// ---------------------------------------------------------------------------
// Pool: h2[n][c] = relu(max_j BN(y1[child[n][j]][c])) on packed bf16 y1.
// ---------------------------------------------------------------------------
__global__ __launch_bounds__(256) void k_pool(
    const unsigned int* __restrict__ y1, const int* __restrict__ child,
    const float* __restrict__ stats, const float* __restrict__ gamma,
    const float* __restrict__ beta, unsigned int* __restrict__ h2) {
  const int tid = threadIdx.x;
  const int wd = tid & 31;
  const int n = blockIdx.x * 8 + (tid >> 5);
  const int c0 = wd * 2, c1 = c0 + 1;
  const int* crow = child + n * 8;
  int ch[8];
#pragma unroll
  for (int j = 0; j < 8; ++j) ch[j] = crow[j];
  unsigned vv[8];
#pragma unroll
  for (int j = 0; j < 8; ++j) vv[j] = y1[ch[j] * 32 + wd];

  float2 ab0 = bn_ab(stats[c0], stats[64 + c0], 1.0f / CN1, gamma[c0], beta[c0]);
  float2 ab1 = bn_ab(stats[c1], stats[64 + c1], 1.0f / CN1, gamma[c1], beta[c1]);
  float mx0 = -INFINITY, mn0 = INFINITY, mx1 = -INFINITY, mn1 = INFINITY;
#pragma unroll
  for (int j = 0; j < 8; ++j) {
    float v0 = __uint_as_float(vv[j] << 16);
    float v1 = __uint_as_float(vv[j] & 0xFFFF0000u);
    mx0 = fmaxf(mx0, v0); mn0 = fminf(mn0, v0);
    mx1 = fmaxf(mx1, v1); mn1 = fminf(mn1, v1);
  }
  float t0 = (ab0.x > 0.f) ? fmaf(ab0.x, mx0, ab0.y) : fmaf(ab0.x, mn0, ab0.y);
  float t1 = (ab1.x > 0.f) ? fmaf(ab1.x, mx1, ab1.y) : fmaf(ab1.x, mn1, ab1.y);
  unsigned o = (unsigned)f2bf(fmaxf(t0, 0.f)) |
               ((unsigned)f2bf(fmaxf(t1, 0.f)) << 16);
  h2[n * 32 + wd] = o;
}

// ---------------------------------------------------------------------------
// MFMA gathered conv, register-direct A (no A-LDS), fragment-layout B
// streamed tap-by-tap through dbuf LDS with ONE lgkm-only barrier per tap.
// A gathers prefetched 2 taps ahead (3-slot rotation), B global 2 taps ahead.
// Block = 32 nodes; wave = 16 nodes x 64 cols (cg selects col-half for
// OUTC=128). Fully unrolled tap loop -> static register indices.
// ---------------------------------------------------------------------------
template <int OUTC>
__global__ __launch_bounds__(OUTC * 2) void k_mconv(
    const unsigned short* __restrict__ src, const int* __restrict__ neigh,
    const unsigned short* __restrict__ Wf, float* __restrict__ out,
    float* __restrict__ stats, int M) {
  constexpr int CG = OUTC / 64;      // col groups (2 or 1)
  constexpr int THREADS = OUTC * 2;  // 256 or 128
  constexpr int PT = CG * 512;       // uint4 per tap
  __shared__ __align__(16) uint4 Bb[2][PT];

  const int tid = threadIdx.x;
  const int lane = tid & 63;
  const int w = tid >> 6;
  const int ng = w & 1, cg = w >> 1;
  const int l15 = lane & 15, lq = lane >> 4;
  const int node = blockIdx.x * 32 + ng * 16 + l15;
  const bool ok = node < M;
  const int* nb = neigh + node * 27;
  const uint4* WfU = (const uint4*)Wf;

  // B global prefetch (taps 0,1)
  uint4 rB[2][4];
#pragma unroll
  for (int j = 0; j < 4; ++j) rB[0][j] = WfU[j * THREADS + tid];
#pragma unroll
  for (int j = 0; j < 4; ++j) rB[1][j] = WfU[PT + j * THREADS + tid];

  // idx window (taps 0..3)
  int ixv[4];
#pragma unroll
  for (int t = 0; t < 4; ++t) ixv[t] = ok ? nb[t] : -1;

  FragU aA[3][2];
#define MGATHER(slot, ixval)                                        \
  {                                                                 \
    int ix_ = (ixval);                                              \
    if (ix_ >= 0) {                                                 \
      const char* bp_ = (const char*)src + (size_t)ix_ * 128 + lq * 16; \
      aA[slot][0].u = *(const uint4*)(bp_);                         \
      aA[slot][1].u = *(const uint4*)(bp_ + 64);                    \
    } else {                                                        \
      aA[slot][0].u = uint4{0u, 0u, 0u, 0u};                        \
      aA[slot][1].u = uint4{0u, 0u, 0u, 0u};                        \
    }                                                               \
  }
  MGATHER(0, ixv[0]);
  MGATHER(1, ixv[1]);

  // B[0] -> LDS (waits rB[0] only; gathers stay in flight)
#pragma unroll
  for (int j = 0; j < 4; ++j) Bb[0][j * THREADS + tid] = rB[0][j];
  sync_lds();

  f32x4 acc[4] = {};
#pragma unroll
  for (int k = 0; k < 27; ++k) {
    // (a) B global prefetch tap k+2 into the buffer freed last tap
    if (k + 2 < 27) {
#pragma unroll
      for (int j = 0; j < 4; ++j)
        rB[k & 1][j] = WfU[(k + 2) * PT + j * THREADS + tid];
      // (b) A gathers tap k+2
      MGATHER((k + 2) % 3, ixv[(k + 2) % 4]);
    }
    // (c) idx tap k+4
    if (k + 4 < 27) ixv[(k + 4) % 4] = ok ? nb[k + 4] : -1;
    // (d) compute tap k (auto-waits aA[k%3] gathers; counted vmcnt)
#pragma unroll
    for (int nf = 0; nf < 4; ++nf) {
      bf16x8 b0 = *(const bf16x8*)&Bb[k & 1][(cg * 4 + nf) * 64 + lane];
      acc[nf] = __builtin_amdgcn_mfma_f32_16x16x32_bf16(aA[k % 3][0].b, b0,
                                                        acc[nf], 0, 0, 0);
      bf16x8 b1 =
          *(const bf16x8*)&Bb[k & 1][(CG * 4 + cg * 4 + nf) * 64 + lane];
      acc[nf] = __builtin_amdgcn_mfma_f32_16x16x32_bf16(aA[k % 3][1].b, b1,
                                                        acc[nf], 0, 0, 0);
    }
    // (e) write B tap k+1 to the other buffer, (f) barrier
    if (k + 1 < 27) {
#pragma unroll
      for (int j = 0; j < 4; ++j)
        Bb[(k + 1) & 1][j * THREADS + tid] = rB[(k + 1) & 1][j];
      sync_lds();
    }
  }
#undef MGATHER

  // store (C/D: col=lane&15, row=(lane>>4)*4+r)
  const int rowbase = blockIdx.x * 32 + ng * 16 + lq * 4;
#pragma unroll
  for (int nf = 0; nf < 4; ++nf) {
    int c = cg * 64 + nf * 16 + l15;
#pragma unroll
    for (int r = 0; r < 4; ++r) {
      int row = rowbase + r;
      if (row < M) out[row * OUTC + c] = acc[nf][r];
    }
  }

  // stats (invalid rows contributed zeros)
#pragma unroll
  for (int nf = 0; nf < 4; ++nf) {
    float s = 0.f, q = 0.f;
#pragma unroll
    for (int r = 0; r < 4; ++r) {
      float v = acc[nf][r];
      s += v; q += v * v;
    }
    s += __shfl_xor(s, 16); s += __shfl_xor(s, 32);
    q += __shfl_xor(q, 16); q += __shfl_xor(q, 32);
    if (lane < 16) {
      int c = cg * 64 + nf * 16 + lane;
      atomicAdd(&stats[c], s);
      atomicAdd(&stats[OUTC + c], q);
    }
  }
}

// ---------------------------------------------------------------------------
// BN+ReLU on y2d channels 0..63 -> out1 (bf16)
// ---------------------------------------------------------------------------
__global__ __launch_bounds__(256) void k_bnrelu(
    const float* __restrict__ y2d, const float* __restrict__ stats,
    const float* __restrict__ gamma, const float* __restrict__ beta,
    unsigned short* __restrict__ out1) {
  int e = blockIdx.x * 256 + threadIdx.x;
  int i = e >> 6, c = e & 63;
  float2 ab = bn_ab(stats[c], stats[128 + c], 1.0f / CN3, gamma[c], beta[c]);
  out1[e] = f2bf(fmaxf(fmaf(ab.x, y2d[i * 128 + c], ab.y), 0.f));
}

// ---------------------------------------------------------------------------
// Final: relu(BN2(y3) + BNd(y2d[:,64:128]))
// ---------------------------------------------------------------------------
__global__ __launch_bounds__(256) void k_final(
    const float* __restrict__ y3, const float* __restrict__ y2d,
    const float* __restrict__ stats2, const float* __restrict__ stats1d,
    const float* __restrict__ g2, const float* __restrict__ b2,
    const float* __restrict__ gd, const float* __restrict__ bd,
    float* __restrict__ dout) {
  int e = blockIdx.x * 256 + threadIdx.x;
  int i = e >> 6, c = e & 63;
  float2 ab2 = bn_ab(stats2[c], stats2[64 + c], 1.0f / CN3, g2[c], b2[c]);
  float2 abd =
      bn_ab(stats1d[64 + c], stats1d[192 + c], 1.0f / CN3, gd[c], bd[c]);
  float o = fmaf(ab2.x, y3[e], ab2.y) + fmaf(abd.x, y2d[i * 128 + 64 + c], abd.y);
  dout[e] = fmaxf(o, 0.f);
}

// ---------------------------------------------------------------------------
extern "C" void kernel_launch(void* const* d_in, const int* in_sizes, int n_in,
                              void* d_out, int out_size, void* d_ws,
                              size_t ws_size, hipStream_t stream) {
  const float* x = (const float*)d_in[0];
  const int* neigh_stem = (const int*)d_in[1];
  const int* pool_child = (const int*)d_in[2];
  const int* neigh_ds = (const int*)d_in[3];
  const int* neigh_res = (const int*)d_in[4];
  const float* W_stem = (const float*)d_in[5];
  const float* g_stem = (const float*)d_in[6];
  const float* b_stem = (const float*)d_in[7];
  const float* W1 = (const float*)d_in[8];
  const float* g1 = (const float*)d_in[9];
  const float* b1 = (const float*)d_in[10];
  const float* W2 = (const float*)d_in[11];
  const float* g2 = (const float*)d_in[12];
  const float* b2 = (const float*)d_in[13];
  const float* Wd = (const float*)d_in[14];
  const float* gd = (const float*)d_in[15];
  const float* bd = (const float*)d_in[16];
  float* out = (float*)d_out;
  float* ws = (float*)d_ws;

  // Workspace layout (float units):
  unsigned short* y1bf = (unsigned short*)ws;              // N1*64 bf16 (9.6M f)
  float* y2d = ws;                                         // N3*128 f32 (reuse)
  unsigned short* out1bf = (unsigned short*)(ws + 3840000);// N3*64 bf16
  float* y3 = ws + 4800000;                                // N3*64 f32
  unsigned short* h2bf = (unsigned short*)(ws + 9600000);  // N2*64 bf16 (2.56M f)
  unsigned int* xbf = (unsigned int*)(ws + 12160000);      // N0*4 bf16 (2M f)
  unsigned short* Wst = (unsigned short*)(ws + 14160000);  // 8192 bf16
  unsigned short* Wdual = (unsigned short*)(ws + 14164096);// 221184 bf16
  unsigned short* Wres = (unsigned short*)(ws + 14274688); // 110592 bf16
  float* stats = ws + 14329984;                            // 512 f32
  float* stats_stem = stats;                               // [128]
  float* stats_1d = stats + 128;                           // [256]
  float* stats_2 = stats + 384;                            // [128]

  hipMemsetAsync(stats, 0, 512 * sizeof(float), stream);

  k_prep_x<<<(CN0 + 255) / 256, 256, 0, stream>>>(x, xbf);
  k_prep_stem<<<(8192 + 255) / 256, 256, 0, stream>>>(W_stem, Wst);
  k_prep_dual<<<(27 * 8192 + 255) / 256, 256, 0, stream>>>(W1, Wd, Wdual);
  k_prep_res<<<(27 * 4096 + 255) / 256, 256, 0, stream>>>(W2, Wres);

  // 4688 tiles of 64 nodes = 2 tiles x 2344 blocks
  k_stem_mfma<<<2344, 256, 0, stream>>>(
      (const unsigned short*)xbf, neigh_stem, Wst, y1bf, stats_stem);
  k_pool<<<CN2 / 8, 256, 0, stream>>>((const unsigned int*)y1bf, pool_child,
                                      stats_stem, g_stem, b_stem,
                                      (unsigned int*)h2bf);
  // 938 blocks of 32 nodes
  k_mconv<128><<<(CN3 + 31) / 32, 256, 0, stream>>>(h2bf, neigh_ds, Wdual,
                                                    y2d, stats_1d, CN3);
  k_bnrelu<<<CN3 * 64 / 256, 256, 0, stream>>>(y2d, stats_1d, g1, b1, out1bf);
  k_mconv<64><<<(CN3 + 31) / 32, 128, 0, stream>>>(out1bf, neigh_res, Wres,
                                                   y3, stats_2, CN3);
  k_final<<<CN3 * 64 / 256, 256, 0, stream>>>(y3, y2d, stats_2, stats_1d, g2,
                                              b2, gd, bd, out);
}

// Round 8
// 400.286 us; speedup vs baseline: 1.0007x; 1.0007x over previous
//
#include <hip/hip_runtime.h>

// Problem constants (match reference setup_inputs)
constexpr int CN0 = 1000000;   // x rows
constexpr int CN1 = 300000;    // stem conv output rows
constexpr int CN2 = 80000;     // pooled rows
constexpr int CN3 = 30000;     // downsampled rows
constexpr float BN_EPS = 1e-5f;

typedef __attribute__((ext_vector_type(8))) short bf16x8;
typedef __attribute__((ext_vector_type(4))) float f32x4;

union FragU { uint4 u; bf16x8 b; };

__device__ __forceinline__ float2 bn_ab(float s, float q, float invn, float gamma, float beta) {
  float m = s * invn;
  float v = fmaf(q, invn, -m * m);
  float rstd = rsqrtf(v + BN_EPS);
  float a = gamma * rstd;
  float b = beta - m * a;
  return make_float2(a, b);
}

// round-to-nearest-even fp32 -> bf16
__device__ __forceinline__ unsigned short f2bf(float f) {
  unsigned u = __float_as_uint(f);
  u += 0x7FFFu + ((u >> 16) & 1u);
  return (unsigned short)(u >> 16);
}

// LDS-only barrier: waits ds ops, does NOT drain vmcnt -> prefetched global
// loads stay in flight across the barrier.
__device__ __forceinline__ void sync_lds() {
  asm volatile("s_waitcnt lgkmcnt(0)" ::: "memory");
  __builtin_amdgcn_s_barrier();
  asm volatile("" ::: "memory");
}

// ---------------------------------------------------------------------------
// Prep: x (f32 [1M][4]) -> xbf (bf16 [1M][4])
// ---------------------------------------------------------------------------
__global__ __launch_bounds__(256) void k_prep_x(
    const float* __restrict__ x, unsigned int* __restrict__ xbf) {
  int i = blockIdx.x * 256 + threadIdx.x;
  if (i >= CN0) return;
  float4 v = *(const float4*)(x + i * 4);
  uint2 p;
  p.x = (unsigned)f2bf(v.x) | ((unsigned)f2bf(v.y) << 16);
  p.y = (unsigned)f2bf(v.z) | ((unsigned)f2bf(v.w) << 16);
  *(uint2*)(xbf + i * 2) = p;
}

// ---------------------------------------------------------------------------
// Prep: W_stem [27][4][64] f32 -> per-lane MFMA B fragments:
// Wf[((ks*4+nf)*64 + lane)*8 + e] = W[k][d], k=ks*32+(lane>>4)*8+e (pad>=108),
// d = nf*16+(lane&15).
// ---------------------------------------------------------------------------
__global__ __launch_bounds__(256) void k_prep_stem(
    const float* __restrict__ W, unsigned short* __restrict__ Wt) {
  int f = blockIdx.x * 256 + threadIdx.x;  // 8192
  if (f >= 8192) return;
  int e = f & 7, lane = (f >> 3) & 63, nf = (f >> 9) & 3, ks = f >> 11;
  int k = ks * 32 + (lane >> 4) * 8 + e;
  int d = nf * 16 + (lane & 15);
  Wt[f] = (k < 108) ? f2bf(W[k * 64 + d]) : (unsigned short)0;
}

// ---------------------------------------------------------------------------
// Prep: dual weights [W1|Wd] -> per-lane fragment layout
// Wf[tap][ks1][nfg(0..7)][lane][e]: cin=ks1*32+(lane>>4)*8+e, d=nfg*16+(lane&15)
// ---------------------------------------------------------------------------
__global__ __launch_bounds__(256) void k_prep_dual(
    const float* __restrict__ W1, const float* __restrict__ Wd,
    unsigned short* __restrict__ Wf) {
  int f = blockIdx.x * 256 + threadIdx.x;  // 27*8192 = 221184
  if (f >= 27 * 8192) return;
  int tap = f >> 13, r = f & 8191;
  int ks1 = (r >> 12) & 1, nfg = (r >> 9) & 7, lane = (r >> 3) & 63, e = r & 7;
  int cin = ks1 * 32 + (lane >> 4) * 8 + e;
  int d = nfg * 16 + (lane & 15);
  float v = (d < 64) ? W1[(tap * 64 + cin) * 64 + d]
                     : Wd[(tap * 64 + cin) * 64 + (d - 64)];
  Wf[f] = f2bf(v);
}

__global__ __launch_bounds__(256) void k_prep_res(
    const float* __restrict__ W2, unsigned short* __restrict__ Wf) {
  int f = blockIdx.x * 256 + threadIdx.x;  // 27*4096 = 110592
  if (f >= 27 * 4096) return;
  int tap = f >> 12, r = f & 4095;
  int ks1 = (r >> 11) & 1, nfg = (r >> 9) & 3, lane = (r >> 3) & 63, e = r & 7;
  int cin = ks1 * 32 + (lane >> 4) * 8 + e;
  int d = nfg * 16 + (lane & 15);
  Wf[f] = f2bf(W2[(tap * 64 + cin) * 64 + d]);
}

// ---------------------------------------------------------------------------
// Stem conv via MFMA, register-direct gather, T=2 tiles/block, full prologue
// prefetch (unchanged from round 7).
// ---------------------------------------------------------------------------
__global__ __launch_bounds__(256) void k_stem_mfma(
    const unsigned short* __restrict__ xbf, const int* __restrict__ neigh,
    const unsigned short* __restrict__ Wf, unsigned short* __restrict__ y1,
    float* __restrict__ stats) {
  __shared__ __align__(16) uint4 Bb[1024];  // 16 KB B fragments
  const int tid = threadIdx.x;
  const int lane = tid & 63;
  const int wv = tid >> 6;
  const int l15 = lane & 15, lq = lane >> 4;
  const int g0 = blockIdx.x * 2;

  uint4 wreg[4];
  {
    const uint4* Ws = (const uint4*)Wf;
#pragma unroll
    for (int j = 0; j < 4; ++j) wreg[j] = Ws[tid + j * 256];
  }

  int idx0[8], idx1[8];
#define LDIDX(g, dst)                                                      \
  {                                                                        \
    int node_ = (g)*64 + wv * 16 + l15;                                    \
    bool rowok_ = node_ < CN1;                                             \
    const int* nb_ = neigh + node_ * 27;                                   \
    _Pragma("unroll") for (int ks_ = 0; ks_ < 4; ++ks_) {                  \
      int tap0_ = ks_ * 8 + lq * 2;                                        \
      dst[ks_ * 2] = (rowok_ && tap0_ < 27) ? nb_[tap0_] : -1;             \
      dst[ks_ * 2 + 1] = (rowok_ && tap0_ + 1 < 27) ? nb_[tap0_ + 1] : -1; \
    }                                                                      \
  }
#define GATHER(idx, frag)                                                  \
  {                                                                        \
    _Pragma("unroll") for (int ks_ = 0; ks_ < 4; ++ks_) {                  \
      uint2 v0_ = {0u, 0u}, v1_ = {0u, 0u};                                \
      if (idx[ks_ * 2] >= 0)                                               \
        v0_ = *(const uint2*)(xbf + idx[ks_ * 2] * 4);                     \
      if (idx[ks_ * 2 + 1] >= 0)                                           \
        v1_ = *(const uint2*)(xbf + idx[ks_ * 2 + 1] * 4);                 \
      frag[ks_].u.x = v0_.x; frag[ks_].u.y = v0_.y;                        \
      frag[ks_].u.z = v1_.x; frag[ks_].u.w = v1_.y;                        \
    }                                                                      \
  }

  LDIDX(g0 + 0, idx0);
  LDIDX(g0 + 1, idx1);
  FragU fA[4], fB[4];
  GATHER(idx0, fA);
  GATHER(idx1, fB);

#pragma unroll
  for (int j = 0; j < 4; ++j) Bb[tid + j * 256] = wreg[j];
  sync_lds();

  float sacc[4] = {0.f, 0.f, 0.f, 0.f};
  float qacc[4] = {0.f, 0.f, 0.f, 0.f};

#pragma unroll
  for (int t = 0; t < 2; ++t) {
    FragU* cur = t ? fB : fA;
    f32x4 acc[4] = {};
#pragma unroll
    for (int ks = 0; ks < 4; ++ks) {
#pragma unroll
      for (int nf = 0; nf < 4; ++nf) {
        bf16x8 b = *(const bf16x8*)&Bb[(ks * 4 + nf) * 64 + lane];
        acc[nf] = __builtin_amdgcn_mfma_f32_16x16x32_bf16(cur[ks].b, b,
                                                          acc[nf], 0, 0, 0);
      }
    }
    int n0 = (g0 + t) * 64 + wv * 16;
#pragma unroll
    for (int nf = 0; nf < 4; ++nf) {
      int c = nf * 16 + l15;
#pragma unroll
      for (int r = 0; r < 4; ++r) {
        int row = n0 + lq * 4 + r;
        float v = acc[nf][r];
        if (row < CN1) y1[row * 64 + c] = f2bf(v);
        sacc[nf] += v;
        qacc[nf] = fmaf(v, v, qacc[nf]);
      }
    }
  }
#undef LDIDX
#undef GATHER

  sync_lds();
  float* S = (float*)Bb;
#pragma unroll
  for (int nf = 0; nf < 4; ++nf) {
    float s = sacc[nf], q = qacc[nf];
    s += __shfl_xor(s, 16); s += __shfl_xor(s, 32);
    q += __shfl_xor(q, 16); q += __shfl_xor(q, 32);
    if (lane < 16) {
      S[wv * 64 + nf * 16 + lane] = s;
      S[256 + wv * 64 + nf * 16 + lane] = q;
    }
  }
  __syncthreads();
  if (tid < 64) {
    float s = S[tid] + S[64 + tid] + S[128 + tid] + S[192 + tid];
    float q = S[256 + tid] + S[320 + tid] + S[384 + tid] + S[448 + tid];
    atomicAdd(&stats[tid], s);
    atomicAdd(&stats[64 + tid], q);
  }
}

// ---------------------------------------------------------------------------
// Pool: h2[n][c] = relu(max_j BN(y1[child[n][j]][c])) on packed bf16 y1.
// ---------------------------------------------------------------------------
__global__ __launch_bounds__(256) void k_pool(
    const unsigned int* __restrict__ y1, const int* __restrict__ child,
    const float* __restrict__ stats, const float* __restrict__ gamma,
    const float* __restrict__ beta, unsigned int* __restrict__ h2) {
  const int tid = threadIdx.x;
  const int wd = tid & 31;
  const int n = blockIdx.x * 8 + (tid >> 5);
  const int c0 = wd * 2, c1 = c0 + 1;
  const int* crow = child + n * 8;
  int ch[8];
#pragma unroll
  for (int j = 0; j < 8; ++j) ch[j] = crow[j];
  unsigned vv[8];
#pragma unroll
  for (int j = 0; j < 8; ++j) vv[j] = y1[ch[j] * 32 + wd];

  float2 ab0 = bn_ab(stats[c0], stats[64 + c0], 1.0f / CN1, gamma[c0], beta[c0]);
  float2 ab1 = bn_ab(stats[c1], stats[64 + c1], 1.0f / CN1, gamma[c1], beta[c1]);
  float mx0 = -INFINITY, mn0 = INFINITY, mx1 = -INFINITY, mn1 = INFINITY;
#pragma unroll
  for (int j = 0; j < 8; ++j) {
    float v0 = __uint_as_float(vv[j] << 16);
    float v1 = __uint_as_float(vv[j] & 0xFFFF0000u);
    mx0 = fmaxf(mx0, v0); mn0 = fminf(mn0, v0);
    mx1 = fmaxf(mx1, v1); mn1 = fminf(mn1, v1);
  }
  float t0 = (ab0.x > 0.f) ? fmaf(ab0.x, mx0, ab0.y) : fmaf(ab0.x, mn0, ab0.y);
  float t1 = (ab1.x > 0.f) ? fmaf(ab1.x, mx1, ab1.y) : fmaf(ab1.x, mn1, ab1.y);
  unsigned o = (unsigned)f2bf(fmaxf(t0, 0.f)) |
               ((unsigned)f2bf(fmaxf(t1, 0.f)) << 16);
  h2[n * 32 + wd] = o;
}

// ---------------------------------------------------------------------------
// MFMA gathered conv, register-direct A, B streamed tap-by-tap through dbuf
// LDS, ONE lgkm-only barrier per tap. STATIC unroll: TAP(k) macro with
// literal k -> every slot index constant-folds (no scratch, rule #20).
// Invariants at tap k entry: A[k%3]=A_k, R[(k+1)&1]=B_{k+1}, Bb[k&1]=B_k,
// I[k%3]=idx_{k+3}.
// ---------------------------------------------------------------------------
template <int OUTC>
__global__ __launch_bounds__(OUTC * 2) void k_mconv(
    const unsigned short* __restrict__ src, const int* __restrict__ neigh,
    const unsigned short* __restrict__ Wf, float* __restrict__ out,
    float* __restrict__ stats, int M) {
  constexpr int CG = OUTC / 64;      // col groups (2 or 1)
  constexpr int THREADS = OUTC * 2;  // 256 or 128
  constexpr int PT = CG * 512;       // uint4 per tap
  constexpr int JPT = PT / THREADS;  // == 4
  static_assert(JPT == 4, "staging width");
  __shared__ __align__(16) uint4 Bb[2][PT];
  __shared__ int nlds[32 * 27];

  const int tid = threadIdx.x;
  const int lane = tid & 63;
  const int w = tid >> 6;
  const int ng = w & 1, cg = w >> 1;
  const int l15 = lane & 15, lq = lane >> 4;

  // stage all neighbor indices (coalesced)
  for (int e = tid; e < 32 * 27; e += THREADS) {
    int row = blockIdx.x * 32 + e / 27;
    nlds[e] = (row < M) ? neigh[row * 27 + e % 27] : -1;
  }

  const uint4* WfU = (const uint4*)Wf;
  uint4 R[2][4];
#pragma unroll
  for (int j = 0; j < 4; ++j) R[0][j] = WfU[j * THREADS + tid];
#pragma unroll
  for (int j = 0; j < 4; ++j) R[1][j] = WfU[PT + j * THREADS + tid];

  sync_lds();  // nlds visible; R loads stay in flight

  const int* myn = &nlds[(ng * 16 + l15) * 27];
  FragU A[3][2];
  int I[3];

#define GATH(s, ixval)                                                     \
  {                                                                        \
    int ix_ = (ixval);                                                     \
    if (ix_ >= 0) {                                                        \
      const char* bp_ = (const char*)src + (size_t)ix_ * 128 + lq * 16;    \
      A[s][0].u = *(const uint4*)bp_;                                      \
      A[s][1].u = *(const uint4*)(bp_ + 64);                               \
    } else {                                                               \
      A[s][0].u = uint4{0u, 0u, 0u, 0u};                                   \
      A[s][1].u = uint4{0u, 0u, 0u, 0u};                                   \
    }                                                                      \
  }

  {
    int i0 = myn[0], i1 = myn[1], i2 = myn[2];
    GATH(0, i0);
    GATH(1, i1);
    GATH(2, i2);
    I[0] = myn[3];
  }
  // B0 -> LDS (waits R[0] only; A gathers are younger, stay in flight)
#pragma unroll
  for (int j = 0; j < 4; ++j) Bb[0][j * THREADS + tid] = R[0][j];
  sync_lds();

  f32x4 acc[4] = {};

#define TAP(k)                                                                \
  {                                                                           \
    if ((k) + 2 < 27) {                                                       \
      _Pragma("unroll") for (int j = 0; j < 4; ++j)                           \
          R[(k) & 1][j] = WfU[((k) + 2) * PT + j * THREADS + tid];            \
    }                                                                         \
    _Pragma("unroll") for (int nf = 0; nf < 4; ++nf) {                        \
      bf16x8 b0 = *(const bf16x8*)&Bb[(k) & 1][(cg * 4 + nf) * 64 + lane];    \
      acc[nf] = __builtin_amdgcn_mfma_f32_16x16x32_bf16(A[(k) % 3][0].b, b0,  \
                                                        acc[nf], 0, 0, 0);    \
      bf16x8 b1 =                                                             \
          *(const bf16x8*)&Bb[(k) & 1][(CG * 4 + cg * 4 + nf) * 64 + lane];   \
      acc[nf] = __builtin_amdgcn_mfma_f32_16x16x32_bf16(A[(k) % 3][1].b, b1,  \
                                                        acc[nf], 0, 0, 0);    \
    }                                                                         \
    if ((k) + 3 < 27) GATH((k) % 3, I[(k) % 3]);                              \
    if ((k) + 4 < 27) I[((k) + 1) % 3] = myn[(k) + 4];                        \
    if ((k) + 1 < 27) {                                                       \
      _Pragma("unroll") for (int j = 0; j < 4; ++j)                           \
          Bb[((k) + 1) & 1][j * THREADS + tid] = R[((k) + 1) & 1][j];         \
      sync_lds();                                                             \
    }                                                                         \
  }

  TAP(0) TAP(1) TAP(2) TAP(3) TAP(4) TAP(5) TAP(6) TAP(7) TAP(8)
  TAP(9) TAP(10) TAP(11) TAP(12) TAP(13) TAP(14) TAP(15) TAP(16) TAP(17)
  TAP(18) TAP(19) TAP(20) TAP(21) TAP(22) TAP(23) TAP(24) TAP(25) TAP(26)
#undef TAP
#undef GATH

  // store (C/D: col=lane&15, row=(lane>>4)*4+r)
  const int rowbase = blockIdx.x * 32 + ng * 16 + lq * 4;
#pragma unroll
  for (int nf = 0; nf < 4; ++nf) {
    int c = cg * 64 + nf * 16 + l15;
#pragma unroll
    for (int r = 0; r < 4; ++r) {
      int row = rowbase + r;
      if (row < M) out[row * OUTC + c] = acc[nf][r];
    }
  }

  // stats (invalid rows contributed zeros)
#pragma unroll
  for (int nf = 0; nf < 4; ++nf) {
    float s = 0.f, q = 0.f;
#pragma unroll
    for (int r = 0; r < 4; ++r) {
      float v = acc[nf][r];
      s += v; q += v * v;
    }
    s += __shfl_xor(s, 16); s += __shfl_xor(s, 32);
    q += __shfl_xor(q, 16); q += __shfl_xor(q, 32);
    if (lane < 16) {
      int c = cg * 64 + nf * 16 + lane;
      atomicAdd(&stats[c], s);
      atomicAdd(&stats[OUTC + c], q);
    }
  }
}

// ---------------------------------------------------------------------------
// BN+ReLU on y2d channels 0..63 -> out1 (bf16)
// ---------------------------------------------------------------------------
__global__ __launch_bounds__(256) void k_bnrelu(
    const float* __restrict__ y2d, const float* __restrict__ stats,
    const float* __restrict__ gamma, const float* __restrict__ beta,
    unsigned short* __restrict__ out1) {
  int e = blockIdx.x * 256 + threadIdx.x;
  int i = e >> 6, c = e & 63;
  float2 ab = bn_ab(stats[c], stats[128 + c], 1.0f / CN3, gamma[c], beta[c]);
  out1[e] = f2bf(fmaxf(fmaf(ab.x, y2d[i * 128 + c], ab.y), 0.f));
}

// ---------------------------------------------------------------------------
// Final: relu(BN2(y3) + BNd(y2d[:,64:128]))
// ---------------------------------------------------------------------------
__global__ __launch_bounds__(256) void k_final(
    const float* __restrict__ y3, const float* __restrict__ y2d,
    const float* __restrict__ stats2, const float* __restrict__ stats1d,
    const float* __restrict__ g2, const float* __restrict__ b2,
    const float* __restrict__ gd, const float* __restrict__ bd,
    float* __restrict__ dout) {
  int e = blockIdx.x * 256 + threadIdx.x;
  int i = e >> 6, c = e & 63;
  float2 ab2 = bn_ab(stats2[c], stats2[64 + c], 1.0f / CN3, g2[c], b2[c]);
  float2 abd =
      bn_ab(stats1d[64 + c], stats1d[192 + c], 1.0f / CN3, gd[c], bd[c]);
  float o = fmaf(ab2.x, y3[e], ab2.y) + fmaf(abd.x, y2d[i * 128 + 64 + c], abd.y);
  dout[e] = fmaxf(o, 0.f);
}

// ---------------------------------------------------------------------------
extern "C" void kernel_launch(void* const* d_in, const int* in_sizes, int n_in,
                              void* d_out, int out_size, void* d_ws,
                              size_t ws_size, hipStream_t stream) {
  const float* x = (const float*)d_in[0];
  const int* neigh_stem = (const int*)d_in[1];
  const int* pool_child = (const int*)d_in[2];
  const int* neigh_ds = (const int*)d_in[3];
  const int* neigh_res = (const int*)d_in[4];
  const float* W_stem = (const float*)d_in[5];
  const float* g_stem = (const float*)d_in[6];
  const float* b_stem = (const float*)d_in[7];
  const float* W1 = (const float*)d_in[8];
  const float* g1 = (const float*)d_in[9];
  const float* b1 = (const float*)d_in[10];
  const float* W2 = (const float*)d_in[11];
  const float* g2 = (const float*)d_in[12];
  const float* b2 = (const float*)d_in[13];
  const float* Wd = (const float*)d_in[14];
  const float* gd = (const float*)d_in[15];
  const float* bd = (const float*)d_in[16];
  float* out = (float*)d_out;
  float* ws = (float*)d_ws;

  // Workspace layout (float units):
  unsigned short* y1bf = (unsigned short*)ws;              // N1*64 bf16 (9.6M f)
  float* y2d = ws;                                         // N3*128 f32 (reuse)
  unsigned short* out1bf = (unsigned short*)(ws + 3840000);// N3*64 bf16
  float* y3 = ws + 4800000;                                // N3*64 f32
  unsigned short* h2bf = (unsigned short*)(ws + 9600000);  // N2*64 bf16 (2.56M f)
  unsigned int* xbf = (unsigned int*)(ws + 12160000);      // N0*4 bf16 (2M f)
  unsigned short* Wst = (unsigned short*)(ws + 14160000);  // 8192 bf16
  unsigned short* Wdual = (unsigned short*)(ws + 14164096);// 221184 bf16
  unsigned short* Wres = (unsigned short*)(ws + 14274688); // 110592 bf16
  float* stats = ws + 14329984;                            // 512 f32
  float* stats_stem = stats;                               // [128]
  float* stats_1d = stats + 128;                           // [256]
  float* stats_2 = stats + 384;                            // [128]

  hipMemsetAsync(stats, 0, 512 * sizeof(float), stream);

  k_prep_x<<<(CN0 + 255) / 256, 256, 0, stream>>>(x, xbf);
  k_prep_stem<<<(8192 + 255) / 256, 256, 0, stream>>>(W_stem, Wst);
  k_prep_dual<<<(27 * 8192 + 255) / 256, 256, 0, stream>>>(W1, Wd, Wdual);
  k_prep_res<<<(27 * 4096 + 255) / 256, 256, 0, stream>>>(W2, Wres);

  // 4688 tiles of 64 nodes = 2 tiles x 2344 blocks
  k_stem_mfma<<<2344, 256, 0, stream>>>(
      (const unsigned short*)xbf, neigh_stem, Wst, y1bf, stats_stem);
  k_pool<<<CN2 / 8, 256, 0, stream>>>((const unsigned int*)y1bf, pool_child,
                                      stats_stem, g_stem, b_stem,
                                      (unsigned int*)h2bf);
  // 938 blocks of 32 nodes
  k_mconv<128><<<(CN3 + 31) / 32, 256, 0, stream>>>(h2bf, neigh_ds, Wdual,
                                                    y2d, stats_1d, CN3);
  k_bnrelu<<<CN3 * 64 / 256, 256, 0, stream>>>(y2d, stats_1d, g1, b1, out1bf);
  k_mconv<64><<<(CN3 + 31) / 32, 128, 0, stream>>>(out1bf, neigh_res, Wres,
                                                   y3, stats_2, CN3);
  k_final<<<CN3 * 64 / 256, 256, 0, stream>>>(y3, y2d, stats_2, stats_1d, g2,
                                              b2, gd, bd, out);
}

// Round 10
// 292.447 us; speedup vs baseline: 1.3696x; 1.3687x over previous
//
#include <hip/hip_runtime.h>

// Problem constants (match reference setup_inputs)
constexpr int CN0 = 1000000;   // x rows
constexpr int CN1 = 300000;    // stem conv output rows
constexpr int CN2 = 80000;     // pooled rows
constexpr int CN3 = 30000;     // downsampled rows
constexpr float BN_EPS = 1e-5f;

typedef __attribute__((ext_vector_type(8))) short bf16x8;
typedef __attribute__((ext_vector_type(4))) float f32x4;

union FragU { uint4 u; bf16x8 b; };

__device__ __forceinline__ float2 bn_ab(float s, float q, float invn, float gamma, float beta) {
  float m = s * invn;
  float v = fmaf(q, invn, -m * m);
  float rstd = rsqrtf(v + BN_EPS);
  float a = gamma * rstd;
  float b = beta - m * a;
  return make_float2(a, b);
}

// round-to-nearest-even fp32 -> bf16
__device__ __forceinline__ unsigned short f2bf(float f) {
  unsigned u = __float_as_uint(f);
  u += 0x7FFFu + ((u >> 16) & 1u);
  return (unsigned short)(u >> 16);
}

// LDS-only barrier: waits ds ops, does NOT drain vmcnt.
__device__ __forceinline__ void sync_lds() {
  asm volatile("s_waitcnt lgkmcnt(0)" ::: "memory");
  __builtin_amdgcn_s_barrier();
  asm volatile("" ::: "memory");
}

// ---------------------------------------------------------------------------
// Prep: x (f32 [1M][4]) -> xbf (bf16 [1M][4])
// ---------------------------------------------------------------------------
__global__ __launch_bounds__(256) void k_prep_x(
    const float* __restrict__ x, unsigned int* __restrict__ xbf) {
  int i = blockIdx.x * 256 + threadIdx.x;
  if (i >= CN0) return;
  float4 v = *(const float4*)(x + i * 4);
  uint2 p;
  p.x = (unsigned)f2bf(v.x) | ((unsigned)f2bf(v.y) << 16);
  p.y = (unsigned)f2bf(v.z) | ((unsigned)f2bf(v.w) << 16);
  *(uint2*)(xbf + i * 2) = p;
}

// ---------------------------------------------------------------------------
// Prep: W_stem [27][4][64] f32 -> per-lane MFMA B fragments:
// Wf[((ks*4+nf)*64 + lane)*8 + e] = W[k][d], k=ks*32+(lane>>4)*8+e (pad>=108),
// d = nf*16+(lane&15).
// ---------------------------------------------------------------------------
__global__ __launch_bounds__(256) void k_prep_stem(
    const float* __restrict__ W, unsigned short* __restrict__ Wt) {
  int f = blockIdx.x * 256 + threadIdx.x;  // 8192
  if (f >= 8192) return;
  int e = f & 7, lane = (f >> 3) & 63, nf = (f >> 9) & 3, ks = f >> 11;
  int k = ks * 32 + (lane >> 4) * 8 + e;
  int d = nf * 16 + (lane & 15);
  Wt[f] = (k < 108) ? f2bf(W[k * 64 + d]) : (unsigned short)0;
}

// ---------------------------------------------------------------------------
// Prep: dual weights [W1|Wd] -> per-lane fragment layout
// Wf[tap][ks1][nfg(0..7)][lane][e]: cin=ks1*32+(lane>>4)*8+e, d=nfg*16+(lane&15)
// ---------------------------------------------------------------------------
__global__ __launch_bounds__(256) void k_prep_dual(
    const float* __restrict__ W1, const float* __restrict__ Wd,
    unsigned short* __restrict__ Wf) {
  int f = blockIdx.x * 256 + threadIdx.x;  // 27*8192 = 221184
  if (f >= 27 * 8192) return;
  int tap = f >> 13, r = f & 8191;
  int ks1 = (r >> 12) & 1, nfg = (r >> 9) & 7, lane = (r >> 3) & 63, e = r & 7;
  int cin = ks1 * 32 + (lane >> 4) * 8 + e;
  int d = nfg * 16 + (lane & 15);
  float v = (d < 64) ? W1[(tap * 64 + cin) * 64 + d]
                     : Wd[(tap * 64 + cin) * 64 + (d - 64)];
  Wf[f] = f2bf(v);
}

__global__ __launch_bounds__(256) void k_prep_res(
    const float* __restrict__ W2, unsigned short* __restrict__ Wf) {
  int f = blockIdx.x * 256 + threadIdx.x;  // 27*4096 = 110592
  if (f >= 27 * 4096) return;
  int tap = f >> 12, r = f & 4095;
  int ks1 = (r >> 11) & 1, nfg = (r >> 9) & 3, lane = (r >> 3) & 63, e = r & 7;
  int cin = ks1 * 32 + (lane >> 4) * 8 + e;
  int d = nfg * 16 + (lane & 15);
  Wf[f] = f2bf(W2[(tap * 64 + cin) * 64 + d]);
}

// ---------------------------------------------------------------------------
// Stem conv via MFMA, register-direct gather, T=2 tiles/block (unchanged,
// round 6/7 verified: 95 us).
// ---------------------------------------------------------------------------
__global__ __launch_bounds__(256) void k_stem_mfma(
    const unsigned short* __restrict__ xbf, const int* __restrict__ neigh,
    const unsigned short* __restrict__ Wf, unsigned short* __restrict__ y1,
    float* __restrict__ stats) {
  __shared__ __align__(16) uint4 Bb[1024];  // 16 KB B fragments
  const int tid = threadIdx.x;
  const int lane = tid & 63;
  const int wv = tid >> 6;
  const int l15 = lane & 15, lq = lane >> 4;
  const int g0 = blockIdx.x * 2;

  uint4 wreg[4];
  {
    const uint4* Ws = (const uint4*)Wf;
#pragma unroll
    for (int j = 0; j < 4; ++j) wreg[j] = Ws[tid + j * 256];
  }

  int idx0[8], idx1[8];
#define LDIDX(g, dst)                                                      \
  {                                                                        \
    int node_ = (g)*64 + wv * 16 + l15;                                    \
    bool rowok_ = node_ < CN1;                                             \
    const int* nb_ = neigh + node_ * 27;                                   \
    _Pragma("unroll") for (int ks_ = 0; ks_ < 4; ++ks_) {                  \
      int tap0_ = ks_ * 8 + lq * 2;                                        \
      dst[ks_ * 2] = (rowok_ && tap0_ < 27) ? nb_[tap0_] : -1;             \
      dst[ks_ * 2 + 1] = (rowok_ && tap0_ + 1 < 27) ? nb_[tap0_ + 1] : -1; \
    }                                                                      \
  }
#define GATHER(idx, frag)                                                  \
  {                                                                        \
    _Pragma("unroll") for (int ks_ = 0; ks_ < 4; ++ks_) {                  \
      uint2 v0_ = {0u, 0u}, v1_ = {0u, 0u};                                \
      if (idx[ks_ * 2] >= 0)                                               \
        v0_ = *(const uint2*)(xbf + idx[ks_ * 2] * 4);                     \
      if (idx[ks_ * 2 + 1] >= 0)                                           \
        v1_ = *(const uint2*)(xbf + idx[ks_ * 2 + 1] * 4);                 \
      frag[ks_].u.x = v0_.x; frag[ks_].u.y = v0_.y;                        \
      frag[ks_].u.z = v1_.x; frag[ks_].u.w = v1_.y;                        \
    }                                                                      \
  }

  LDIDX(g0 + 0, idx0);
  LDIDX(g0 + 1, idx1);
  FragU fA[4], fB[4];
  GATHER(idx0, fA);
  GATHER(idx1, fB);

#pragma unroll
  for (int j = 0; j < 4; ++j) Bb[tid + j * 256] = wreg[j];
  sync_lds();

  float sacc[4] = {0.f, 0.f, 0.f, 0.f};
  float qacc[4] = {0.f, 0.f, 0.f, 0.f};

#pragma unroll
  for (int t = 0; t < 2; ++t) {
    FragU* cur = t ? fB : fA;
    f32x4 acc[4] = {};
#pragma unroll
    for (int ks = 0; ks < 4; ++ks) {
#pragma unroll
      for (int nf = 0; nf < 4; ++nf) {
        bf16x8 b = *(const bf16x8*)&Bb[(ks * 4 + nf) * 64 + lane];
        acc[nf] = __builtin_amdgcn_mfma_f32_16x16x32_bf16(cur[ks].b, b,
                                                          acc[nf], 0, 0, 0);
      }
    }
    int n0 = (g0 + t) * 64 + wv * 16;
#pragma unroll
    for (int nf = 0; nf < 4; ++nf) {
      int c = nf * 16 + l15;
#pragma unroll
      for (int r = 0; r < 4; ++r) {
        int row = n0 + lq * 4 + r;
        float v = acc[nf][r];
        if (row < CN1) y1[row * 64 + c] = f2bf(v);
        sacc[nf] += v;
        qacc[nf] = fmaf(v, v, qacc[nf]);
      }
    }
  }
#undef LDIDX
#undef GATHER

  sync_lds();
  float* S = (float*)Bb;
#pragma unroll
  for (int nf = 0; nf < 4; ++nf) {
    float s = sacc[nf], q = qacc[nf];
    s += __shfl_xor(s, 16); s += __shfl_xor(s, 32);
    q += __shfl_xor(q, 16); q += __shfl_xor(q, 32);
    if (lane < 16) {
      S[wv * 64 + nf * 16 + lane] = s;
      S[256 + wv * 64 + nf * 16 + lane] = q;
    }
  }
  __syncthreads();
  if (tid < 64) {
    float s = S[tid] + S[64 + tid] + S[128 + tid] + S[192 + tid];
    float q = S[256 + tid] + S[320 + tid] + S[384 + tid] + S[448 + tid];
    atomicAdd(&stats[tid], s);
    atomicAdd(&stats[64 + tid], q);
  }
}

// ---------------------------------------------------------------------------
// Pool: h2[n][c] = relu(max_j BN(y1[child[n][j]][c])) on packed bf16 y1.
// ---------------------------------------------------------------------------
__global__ __launch_bounds__(256) void k_pool(
    const unsigned int* __restrict__ y1, const int* __restrict__ child,
    const float* __restrict__ stats, const float* __restrict__ gamma,
    const float* __restrict__ beta, unsigned int* __restrict__ h2) {
  const int tid = threadIdx.x;
  const int wd = tid & 31;
  const int n = blockIdx.x * 8 + (tid >> 5);
  const int c0 = wd * 2, c1 = c0 + 1;
  const int* crow = child + n * 8;
  int ch[8];
#pragma unroll
  for (int j = 0; j < 8; ++j) ch[j] = crow[j];
  unsigned vv[8];
#pragma unroll
  for (int j = 0; j < 8; ++j) vv[j] = y1[ch[j] * 32 + wd];

  float2 ab0 = bn_ab(stats[c0], stats[64 + c0], 1.0f / CN1, gamma[c0], beta[c0]);
  float2 ab1 = bn_ab(stats[c1], stats[64 + c1], 1.0f / CN1, gamma[c1], beta[c1]);
  float mx0 = -INFINITY, mn0 = INFINITY, mx1 = -INFINITY, mn1 = INFINITY;
#pragma unroll
  for (int j = 0; j < 8; ++j) {
    float v0 = __uint_as_float(vv[j] << 16);
    float v1 = __uint_as_float(vv[j] & 0xFFFF0000u);
    mx0 = fmaxf(mx0, v0); mn0 = fminf(mn0, v0);
    mx1 = fmaxf(mx1, v1); mn1 = fminf(mn1, v1);
  }
  float t0 = (ab0.x > 0.f) ? fmaf(ab0.x, mx0, ab0.y) : fmaf(ab0.x, mn0, ab0.y);
  float t1 = (ab1.x > 0.f) ? fmaf(ab1.x, mx1, ab1.y) : fmaf(ab1.x, mn1, ab1.y);
  unsigned o = (unsigned)f2bf(fmaxf(t0, 0.f)) |
               ((unsigned)f2bf(fmaxf(t1, 0.f)) << 16);
  h2[n * 32 + wd] = o;
}

// ---------------------------------------------------------------------------
// MFMA gathered conv, BARRIER-FREE / LDS-FREE / ARRAY-FREE.
// B fragments read directly from global (L2-resident, 432/110 KB total),
// prefetched one tap ahead into named regs (qa*/qb*). A gathered 3 taps deep
// into named regs (a0/a1/a2). All 27 neighbor indices loaded as named
// scalars in the prologue. No local arrays, no runtime indices, no barriers.
// NOTE: all numeric token-pastes parenthesized -> (QP##0).u, never QP##0.u
// (0.u lexes as one pp-number token and the paste is ill-formed).
// ---------------------------------------------------------------------------
template <int OUTC>
__global__ __launch_bounds__(OUTC * 2) void k_mconv(
    const unsigned short* __restrict__ src, const int* __restrict__ neigh,
    const unsigned short* __restrict__ Wf, float* __restrict__ out,
    float* __restrict__ stats, int M) {
  constexpr int CG = OUTC / 64;  // col groups per 64 outs (2 or 1)
  constexpr int PT = CG * 512;   // uint4 per tap
  constexpr int K1 = 4 * CG;     // ks1=1 fragment offset (frags)

  const int tid = threadIdx.x;
  const int lane = tid & 63;
  const int w = tid >> 6;
  const int ng = w & 1, cg = w >> 1;
  const int l15 = lane & 15, lq = lane >> 4;
  const int node = blockIdx.x * 32 + ng * 16 + l15;
  const bool ok = node < M;
  const int* myn = neigh + node * 27;
  const uint4* WfU = (const uint4*)Wf;
  const int cg4 = cg * 4;

  // all 27 neighbor indices as named scalars (one branch, 27 indep loads)
  int i0 = -1, i1 = -1, i2 = -1, i3 = -1, i4 = -1, i5 = -1, i6 = -1,
      i7 = -1, i8 = -1, i9 = -1, i10 = -1, i11 = -1, i12 = -1, i13 = -1,
      i14 = -1, i15 = -1, i16 = -1, i17 = -1, i18 = -1, i19 = -1, i20 = -1,
      i21 = -1, i22 = -1, i23 = -1, i24 = -1, i25 = -1, i26 = -1;
  if (ok) {
    i0 = myn[0];   i1 = myn[1];   i2 = myn[2];   i3 = myn[3];
    i4 = myn[4];   i5 = myn[5];   i6 = myn[6];   i7 = myn[7];
    i8 = myn[8];   i9 = myn[9];   i10 = myn[10]; i11 = myn[11];
    i12 = myn[12]; i13 = myn[13]; i14 = myn[14]; i15 = myn[15];
    i16 = myn[16]; i17 = myn[17]; i18 = myn[18]; i19 = myn[19];
    i20 = myn[20]; i21 = myn[21]; i22 = myn[22]; i23 = myn[23];
    i24 = myn[24]; i25 = myn[25]; i26 = myn[26];
  }

  FragU a0l, a0h, a1l, a1h, a2l, a2h;
  FragU qa0, qa1, qa2, qa3, qa4, qa5, qa6, qa7;
  FragU qb0, qb1, qb2, qb3, qb4, qb5, qb6, qb7;
  f32x4 acc0 = {0.f, 0.f, 0.f, 0.f};
  f32x4 acc1 = {0.f, 0.f, 0.f, 0.f};
  f32x4 acc2 = {0.f, 0.f, 0.f, 0.f};
  f32x4 acc3 = {0.f, 0.f, 0.f, 0.f};

#define GATH2(AL, AH, ix)                                                  \
  {                                                                        \
    int ix_ = (ix);                                                        \
    if (ix_ >= 0) {                                                        \
      const char* bp_ = (const char*)src + (size_t)ix_ * 128 + lq * 16;    \
      AL.u = *(const uint4*)bp_;                                           \
      AH.u = *(const uint4*)(bp_ + 64);                                    \
    } else {                                                               \
      AL.u = uint4{0u, 0u, 0u, 0u};                                        \
      AH.u = uint4{0u, 0u, 0u, 0u};                                        \
    }                                                                      \
  }

#define LDB(QP, k)                                                         \
  {                                                                        \
    const uint4* bp_ = WfU + ((k)*PT + cg4 * 64 + lane);                   \
    (QP##0).u = bp_[0];                                                    \
    (QP##1).u = bp_[64];                                                   \
    (QP##2).u = bp_[128];                                                  \
    (QP##3).u = bp_[192];                                                  \
    (QP##4).u = bp_[K1 * 64];                                              \
    (QP##5).u = bp_[K1 * 64 + 64];                                         \
    (QP##6).u = bp_[K1 * 64 + 128];                                        \
    (QP##7).u = bp_[K1 * 64 + 192];                                        \
  }

#define MM(AP, QP)                                                            \
  acc0 = __builtin_amdgcn_mfma_f32_16x16x32_bf16((AP##l).b, (QP##0).b, acc0, 0, 0, 0); \
  acc0 = __builtin_amdgcn_mfma_f32_16x16x32_bf16((AP##h).b, (QP##4).b, acc0, 0, 0, 0); \
  acc1 = __builtin_amdgcn_mfma_f32_16x16x32_bf16((AP##l).b, (QP##1).b, acc1, 0, 0, 0); \
  acc1 = __builtin_amdgcn_mfma_f32_16x16x32_bf16((AP##h).b, (QP##5).b, acc1, 0, 0, 0); \
  acc2 = __builtin_amdgcn_mfma_f32_16x16x32_bf16((AP##l).b, (QP##2).b, acc2, 0, 0, 0); \
  acc2 = __builtin_amdgcn_mfma_f32_16x16x32_bf16((AP##h).b, (QP##6).b, acc2, 0, 0, 0); \
  acc3 = __builtin_amdgcn_mfma_f32_16x16x32_bf16((AP##l).b, (QP##3).b, acc3, 0, 0, 0); \
  acc3 = __builtin_amdgcn_mfma_f32_16x16x32_bf16((AP##h).b, (QP##7).b, acc3, 0, 0, 0);

// TAP(k): prefetch B for k+1 into QN, MFMA tap k (AP x QP), then gather
// tap k+3 into the just-freed AP slot (idx INX). All names static.
#define TAP(k, AP, QP, QN, INX)          \
  {                                      \
    if ((k) + 1 < 27) LDB(QN, (k) + 1)   \
    MM(AP, QP)                           \
    if ((k) + 3 < 27) GATH2(AP##l, AP##h, INX) \
  }

  // prologue: gathers taps 0..2, B tap 0
  GATH2(a0l, a0h, i0)
  GATH2(a1l, a1h, i1)
  GATH2(a2l, a2h, i2)
  LDB(qa, 0)

  TAP(0, a0, qa, qb, i3)
  TAP(1, a1, qb, qa, i4)
  TAP(2, a2, qa, qb, i5)
  TAP(3, a0, qb, qa, i6)
  TAP(4, a1, qa, qb, i7)
  TAP(5, a2, qb, qa, i8)
  TAP(6, a0, qa, qb, i9)
  TAP(7, a1, qb, qa, i10)
  TAP(8, a2, qa, qb, i11)
  TAP(9, a0, qb, qa, i12)
  TAP(10, a1, qa, qb, i13)
  TAP(11, a2, qb, qa, i14)
  TAP(12, a0, qa, qb, i15)
  TAP(13, a1, qb, qa, i16)
  TAP(14, a2, qa, qb, i17)
  TAP(15, a0, qb, qa, i18)
  TAP(16, a1, qa, qb, i19)
  TAP(17, a2, qb, qa, i20)
  TAP(18, a0, qa, qb, i21)
  TAP(19, a1, qb, qa, i22)
  TAP(20, a2, qa, qb, i23)
  TAP(21, a0, qb, qa, i24)
  TAP(22, a1, qa, qb, i25)
  TAP(23, a2, qb, qa, i26)
  TAP(24, a0, qa, qb, i0)
  TAP(25, a1, qb, qa, i0)
  TAP(26, a2, qa, qb, i0)
#undef TAP
#undef MM
#undef LDB
#undef GATH2

  // store (C/D: col=lane&15, row=(lane>>4)*4+r)
  const int rowbase = blockIdx.x * 32 + ng * 16 + lq * 4;
#pragma unroll
  for (int nf = 0; nf < 4; ++nf) {
    f32x4 a = (nf == 0) ? acc0 : (nf == 1) ? acc1 : (nf == 2) ? acc2 : acc3;
    int c = cg * 64 + nf * 16 + l15;
#pragma unroll
    for (int r = 0; r < 4; ++r) {
      int row = rowbase + r;
      if (row < M) out[row * OUTC + c] = a[r];
    }
  }

  // stats (invalid rows contributed zeros)
#pragma unroll
  for (int nf = 0; nf < 4; ++nf) {
    f32x4 a = (nf == 0) ? acc0 : (nf == 1) ? acc1 : (nf == 2) ? acc2 : acc3;
    float s = 0.f, q = 0.f;
#pragma unroll
    for (int r = 0; r < 4; ++r) {
      float v = a[r];
      s += v; q += v * v;
    }
    s += __shfl_xor(s, 16); s += __shfl_xor(s, 32);
    q += __shfl_xor(q, 16); q += __shfl_xor(q, 32);
    if (lane < 16) {
      int c = cg * 64 + nf * 16 + lane;
      atomicAdd(&stats[c], s);
      atomicAdd(&stats[OUTC + c], q);
    }
  }
}

// ---------------------------------------------------------------------------
// BN+ReLU on y2d channels 0..63 -> out1 (bf16)
// ---------------------------------------------------------------------------
__global__ __launch_bounds__(256) void k_bnrelu(
    const float* __restrict__ y2d, const float* __restrict__ stats,
    const float* __restrict__ gamma, const float* __restrict__ beta,
    unsigned short* __restrict__ out1) {
  int e = blockIdx.x * 256 + threadIdx.x;
  int i = e >> 6, c = e & 63;
  float2 ab = bn_ab(stats[c], stats[128 + c], 1.0f / CN3, gamma[c], beta[c]);
  out1[e] = f2bf(fmaxf(fmaf(ab.x, y2d[i * 128 + c], ab.y), 0.f));
}

// ---------------------------------------------------------------------------
// Final: relu(BN2(y3) + BNd(y2d[:,64:128]))
// ---------------------------------------------------------------------------
__global__ __launch_bounds__(256) void k_final(
    const float* __restrict__ y3, const float* __restrict__ y2d,
    const float* __restrict__ stats2, const float* __restrict__ stats1d,
    const float* __restrict__ g2, const float* __restrict__ b2,
    const float* __restrict__ gd, const float* __restrict__ bd,
    float* __restrict__ dout) {
  int e = blockIdx.x * 256 + threadIdx.x;
  int i = e >> 6, c = e & 63;
  float2 ab2 = bn_ab(stats2[c], stats2[64 + c], 1.0f / CN3, g2[c], b2[c]);
  float2 abd =
      bn_ab(stats1d[64 + c], stats1d[192 + c], 1.0f / CN3, gd[c], bd[c]);
  float o = fmaf(ab2.x, y3[e], ab2.y) + fmaf(abd.x, y2d[i * 128 + 64 + c], abd.y);
  dout[e] = fmaxf(o, 0.f);
}

// ---------------------------------------------------------------------------
extern "C" void kernel_launch(void* const* d_in, const int* in_sizes, int n_in,
                              void* d_out, int out_size, void* d_ws,
                              size_t ws_size, hipStream_t stream) {
  const float* x = (const float*)d_in[0];
  const int* neigh_stem = (const int*)d_in[1];
  const int* pool_child = (const int*)d_in[2];
  const int* neigh_ds = (const int*)d_in[3];
  const int* neigh_res = (const int*)d_in[4];
  const float* W_stem = (const float*)d_in[5];
  const float* g_stem = (const float*)d_in[6];
  const float* b_stem = (const float*)d_in[7];
  const float* W1 = (const float*)d_in[8];
  const float* g1 = (const float*)d_in[9];
  const float* b1 = (const float*)d_in[10];
  const float* W2 = (const float*)d_in[11];
  const float* g2 = (const float*)d_in[12];
  const float* b2 = (const float*)d_in[13];
  const float* Wd = (const float*)d_in[14];
  const float* gd = (const float*)d_in[15];
  const float* bd = (const float*)d_in[16];
  float* out = (float*)d_out;
  float* ws = (float*)d_ws;

  // Workspace layout (float units):
  unsigned short* y1bf = (unsigned short*)ws;              // N1*64 bf16 (9.6M f)
  float* y2d = ws;                                         // N3*128 f32 (reuse)
  unsigned short* out1bf = (unsigned short*)(ws + 3840000);// N3*64 bf16
  float* y3 = ws + 4800000;                                // N3*64 f32
  unsigned short* h2bf = (unsigned short*)(ws + 9600000);  // N2*64 bf16 (2.56M f)
  unsigned int* xbf = (unsigned int*)(ws + 12160000);      // N0*4 bf16 (2M f)
  unsigned short* Wst = (unsigned short*)(ws + 14160000);  // 8192 bf16
  unsigned short* Wdual = (unsigned short*)(ws + 14164096);// 221184 bf16
  unsigned short* Wres = (unsigned short*)(ws + 14274688); // 110592 bf16
  float* stats = ws + 14329984;                            // 512 f32
  float* stats_stem = stats;                               // [128]
  float* stats_1d = stats + 128;                           // [256]
  float* stats_2 = stats + 384;                            // [128]

  hipMemsetAsync(stats, 0, 512 * sizeof(float), stream);

  k_prep_x<<<(CN0 + 255) / 256, 256, 0, stream>>>(x, xbf);
  k_prep_stem<<<(8192 + 255) / 256, 256, 0, stream>>>(W_stem, Wst);
  k_prep_dual<<<(27 * 8192 + 255) / 256, 256, 0, stream>>>(W1, Wd, Wdual);
  k_prep_res<<<(27 * 4096 + 255) / 256, 256, 0, stream>>>(W2, Wres);

  // 4688 tiles of 64 nodes = 2 tiles x 2344 blocks
  k_stem_mfma<<<2344, 256, 0, stream>>>(
      (const unsigned short*)xbf, neigh_stem, Wst, y1bf, stats_stem);
  k_pool<<<CN2 / 8, 256, 0, stream>>>((const unsigned int*)y1bf, pool_child,
                                      stats_stem, g_stem, b_stem,
                                      (unsigned int*)h2bf);
  // 938 blocks of 32 nodes
  k_mconv<128><<<(CN3 + 31) / 32, 256, 0, stream>>>(h2bf, neigh_ds, Wdual,
                                                    y2d, stats_1d, CN3);
  k_bnrelu<<<CN3 * 64 / 256, 256, 0, stream>>>(y2d, stats_1d, g1, b1, out1bf);
  k_mconv<64><<<(CN3 + 31) / 32, 128, 0, stream>>>(out1bf, neigh_res, Wres,
                                                   y3, stats_2, CN3);
  k_final<<<CN3 * 64 / 256, 256, 0, stream>>>(y3, y2d, stats_2, stats_1d, g2,
                                              b2, gd, bd, out);
}

// Round 11
// 239.061 us; speedup vs baseline: 1.6755x; 1.2233x over previous
//
#include <hip/hip_runtime.h>

// Problem constants (match reference setup_inputs)
constexpr int CN0 = 1000000;   // x rows
constexpr int CN1 = 300000;    // stem conv output rows
constexpr int CN2 = 80000;     // pooled rows
constexpr int CN3 = 30000;     // downsampled rows
constexpr float BN_EPS = 1e-5f;

typedef __attribute__((ext_vector_type(8))) short bf16x8;
typedef __attribute__((ext_vector_type(4))) float f32x4;

union FragU { uint4 u; bf16x8 b; };

__device__ __forceinline__ float2 bn_ab(float s, float q, float invn, float gamma, float beta) {
  float m = s * invn;
  float v = fmaf(q, invn, -m * m);
  float rstd = rsqrtf(v + BN_EPS);
  float a = gamma * rstd;
  float b = beta - m * a;
  return make_float2(a, b);
}

// round-to-nearest-even fp32 -> bf16
__device__ __forceinline__ unsigned short f2bf(float f) {
  unsigned u = __float_as_uint(f);
  u += 0x7FFFu + ((u >> 16) & 1u);
  return (unsigned short)(u >> 16);
}

// LDS-only barrier: waits ds ops, does NOT drain vmcnt -> prefetched global
// loads stay in flight across the barrier.
__device__ __forceinline__ void sync_lds() {
  asm volatile("s_waitcnt lgkmcnt(0)" ::: "memory");
  __builtin_amdgcn_s_barrier();
  asm volatile("" ::: "memory");
}

// ---------------------------------------------------------------------------
// Prep: x (f32 [1M][4]) -> xbf (bf16 [1M][4])
// ---------------------------------------------------------------------------
__global__ __launch_bounds__(256) void k_prep_x(
    const float* __restrict__ x, unsigned int* __restrict__ xbf) {
  int i = blockIdx.x * 256 + threadIdx.x;
  if (i >= CN0) return;
  float4 v = *(const float4*)(x + i * 4);
  uint2 p;
  p.x = (unsigned)f2bf(v.x) | ((unsigned)f2bf(v.y) << 16);
  p.y = (unsigned)f2bf(v.z) | ((unsigned)f2bf(v.w) << 16);
  *(uint2*)(xbf + i * 2) = p;
}

// ---------------------------------------------------------------------------
// Prep: W_stem [27][4][64] f32 -> per-lane MFMA B fragments:
// Wf[((ks*4+nf)*64 + lane)*8 + e] = W[k][d], k=ks*32+(lane>>4)*8+e (pad>=108),
// d = nf*16+(lane&15).
// ---------------------------------------------------------------------------
__global__ __launch_bounds__(256) void k_prep_stem(
    const float* __restrict__ W, unsigned short* __restrict__ Wt) {
  int f = blockIdx.x * 256 + threadIdx.x;  // 8192
  if (f >= 8192) return;
  int e = f & 7, lane = (f >> 3) & 63, nf = (f >> 9) & 3, ks = f >> 11;
  int k = ks * 32 + (lane >> 4) * 8 + e;
  int d = nf * 16 + (lane & 15);
  Wt[f] = (k < 108) ? f2bf(W[k * 64 + d]) : (unsigned short)0;
}

// ---------------------------------------------------------------------------
// Prep: dual weights [W1|Wd] -> per-lane fragment layout
// Wf[tap][ks1][nfg(0..7)][lane][e]: cin=ks1*32+(lane>>4)*8+e, d=nfg*16+(lane&15)
// ---------------------------------------------------------------------------
__global__ __launch_bounds__(256) void k_prep_dual(
    const float* __restrict__ W1, const float* __restrict__ Wd,
    unsigned short* __restrict__ Wf) {
  int f = blockIdx.x * 256 + threadIdx.x;  // 27*8192 = 221184
  if (f >= 27 * 8192) return;
  int tap = f >> 13, r = f & 8191;
  int ks1 = (r >> 12) & 1, nfg = (r >> 9) & 7, lane = (r >> 3) & 63, e = r & 7;
  int cin = ks1 * 32 + (lane >> 4) * 8 + e;
  int d = nfg * 16 + (lane & 15);
  float v = (d < 64) ? W1[(tap * 64 + cin) * 64 + d]
                     : Wd[(tap * 64 + cin) * 64 + (d - 64)];
  Wf[f] = f2bf(v);
}

__global__ __launch_bounds__(256) void k_prep_res(
    const float* __restrict__ W2, unsigned short* __restrict__ Wf) {
  int f = blockIdx.x * 256 + threadIdx.x;  // 27*4096 = 110592
  if (f >= 27 * 4096) return;
  int tap = f >> 12, r = f & 4095;
  int ks1 = (r >> 11) & 1, nfg = (r >> 9) & 3, lane = (r >> 3) & 63, e = r & 7;
  int cin = ks1 * 32 + (lane >> 4) * 8 + e;
  int d = nfg * 16 + (lane & 15);
  Wf[f] = f2bf(W2[(tap * 64 + cin) * 64 + d]);
}

// ---------------------------------------------------------------------------
// Stem conv via MFMA — r6 T=4 version verbatim (measured 95 us).
// ---------------------------------------------------------------------------
__global__ __launch_bounds__(256) void k_stem_mfma(
    const unsigned short* __restrict__ xbf, const int* __restrict__ neigh,
    const unsigned short* __restrict__ Wf, unsigned short* __restrict__ y1,
    float* __restrict__ stats) {
  constexpr int T = 4;  // tiles (of 64 nodes) per block; 1172 blocks
  __shared__ __align__(16) uint4 Bb[1024];  // 16 KB: B fragments, staged once
  const int tid = threadIdx.x;
  const int lane = tid & 63;
  const int wv = tid >> 6;
  const int l15 = lane & 15, lq = lane >> 4;
  const int g0 = blockIdx.x * T;

  // Stage B fragments (linear copy, conflict-free reads later)
  {
    const uint4* Wsrc = (const uint4*)Wf;
#pragma unroll
    for (int j = 0; j < 4; ++j) Bb[tid + j * 256] = Wsrc[tid + j * 256];
  }
  __syncthreads();  // nothing valuable in flight yet

  int idxA[8], idxB[8];
  FragU fragA[4], fragB[4];

#define LDIDX(g, dst)                                                   \
  {                                                                     \
    int node_ = (g)*64 + wv * 16 + l15;                                 \
    bool rowok_ = node_ < CN1;                                          \
    const int* nb_ = neigh + node_ * 27;                                \
    _Pragma("unroll") for (int ks_ = 0; ks_ < 4; ++ks_) {               \
      int tap0_ = ks_ * 8 + lq * 2;                                     \
      dst[ks_ * 2] = (rowok_ && tap0_ < 27) ? nb_[tap0_] : -1;          \
      dst[ks_ * 2 + 1] = (rowok_ && tap0_ + 1 < 27) ? nb_[tap0_ + 1] : -1; \
    }                                                                   \
  }

#define GATHER(idx, frag)                                               \
  {                                                                     \
    _Pragma("unroll") for (int ks_ = 0; ks_ < 4; ++ks_) {               \
      uint2 v0_ = {0u, 0u}, v1_ = {0u, 0u};                             \
      if (idx[ks_ * 2] >= 0)                                            \
        v0_ = *(const uint2*)(xbf + idx[ks_ * 2] * 4);                  \
      if (idx[ks_ * 2 + 1] >= 0)                                        \
        v1_ = *(const uint2*)(xbf + idx[ks_ * 2 + 1] * 4);              \
      frag[ks_].u.x = v0_.x; frag[ks_].u.y = v0_.y;                     \
      frag[ks_].u.z = v1_.x; frag[ks_].u.w = v1_.y;                     \
    }                                                                   \
  }

  // prologue: tile0 idx -> tile0 gathers -> tile1 idx
  LDIDX(0 + g0, idxA);
  GATHER(idxA, fragA);
  LDIDX(1 + g0, idxB);

  float sacc[4] = {0.f, 0.f, 0.f, 0.f};
  float qacc[4] = {0.f, 0.f, 0.f, 0.f};

#pragma unroll
  for (int t = 0; t < T; ++t) {
    FragU* cur = (t & 1) ? fragB : fragA;
    FragU* nxt = (t & 1) ? fragA : fragB;
    int* idn = (t & 1) ? idxA : idxB;    // idx of tile t+1 (already loaded)
    int* idn2 = (t & 1) ? idxB : idxA;   // slot for idx of tile t+2
    // issue next tile's gathers + idx loads (ride latency under compute)
    if (t + 1 < T) GATHER(idn, nxt);
    if (t + 2 < T) LDIDX(g0 + t + 2, idn2);

    // compute: 4 K-substeps x 4 col-fragments; B from LDS
    f32x4 acc[4] = {};
#pragma unroll
    for (int ks = 0; ks < 4; ++ks) {
#pragma unroll
      for (int nf = 0; nf < 4; ++nf) {
        bf16x8 b = *(const bf16x8*)&Bb[(ks * 4 + nf) * 64 + lane];
        acc[nf] = __builtin_amdgcn_mfma_f32_16x16x32_bf16(cur[ks].b, b,
                                                          acc[nf], 0, 0, 0);
      }
    }

    // epilogue: store + register stats. C/D: col=lane&15, row=(lane>>4)*4+r
    int n0 = (g0 + t) * 64 + wv * 16;
#pragma unroll
    for (int nf = 0; nf < 4; ++nf) {
      int c = nf * 16 + l15;
#pragma unroll
      for (int r = 0; r < 4; ++r) {
        int row = n0 + lq * 4 + r;
        float v = acc[nf][r];
        if (row < CN1) y1[row * 64 + c] = f2bf(v);
        sacc[nf] += v;
        qacc[nf] = fmaf(v, v, qacc[nf]);
      }
    }
  }
#undef LDIDX
#undef GATHER

  // cross-wave stats reduction (reuse Bb as scratch), one atomic set/block
  __syncthreads();
  float* S = (float*)Bb;  // [2][4 waves][64 cols]
#pragma unroll
  for (int nf = 0; nf < 4; ++nf) {
    float s = sacc[nf], q = qacc[nf];
    s += __shfl_xor(s, 16); s += __shfl_xor(s, 32);
    q += __shfl_xor(q, 16); q += __shfl_xor(q, 32);
    if (lane < 16) {
      S[wv * 64 + nf * 16 + lane] = s;
      S[256 + wv * 64 + nf * 16 + lane] = q;
    }
  }
  __syncthreads();
  if (tid < 64) {
    float s = S[tid] + S[64 + tid] + S[128 + tid] + S[192 + tid];
    float q = S[256 + tid] + S[320 + tid] + S[384 + tid] + S[448 + tid];
    atomicAdd(&stats[tid], s);
    atomicAdd(&stats[64 + tid], q);
  }
}

// ---------------------------------------------------------------------------
// Pool: h2[n][c] = relu(max_j BN(y1[child[n][j]][c])) on packed bf16 y1.
// ---------------------------------------------------------------------------
__global__ __launch_bounds__(256) void k_pool(
    const unsigned int* __restrict__ y1, const int* __restrict__ child,
    const float* __restrict__ stats, const float* __restrict__ gamma,
    const float* __restrict__ beta, unsigned int* __restrict__ h2) {
  const int tid = threadIdx.x;
  const int wd = tid & 31;
  const int n = blockIdx.x * 8 + (tid >> 5);
  const int c0 = wd * 2, c1 = c0 + 1;
  const int* crow = child + n * 8;
  int ch[8];
#pragma unroll
  for (int j = 0; j < 8; ++j) ch[j] = crow[j];
  unsigned vv[8];
#pragma unroll
  for (int j = 0; j < 8; ++j) vv[j] = y1[ch[j] * 32 + wd];

  float2 ab0 = bn_ab(stats[c0], stats[64 + c0], 1.0f / CN1, gamma[c0], beta[c0]);
  float2 ab1 = bn_ab(stats[c1], stats[64 + c1], 1.0f / CN1, gamma[c1], beta[c1]);
  float mx0 = -INFINITY, mn0 = INFINITY, mx1 = -INFINITY, mn1 = INFINITY;
#pragma unroll
  for (int j = 0; j < 8; ++j) {
    float v0 = __uint_as_float(vv[j] << 16);
    float v1 = __uint_as_float(vv[j] & 0xFFFF0000u);
    mx0 = fmaxf(mx0, v0); mn0 = fminf(mn0, v0);
    mx1 = fmaxf(mx1, v1); mn1 = fminf(mn1, v1);
  }
  float t0 = (ab0.x > 0.f) ? fmaf(ab0.x, mx0, ab0.y) : fmaf(ab0.x, mn0, ab0.y);
  float t1 = (ab1.x > 0.f) ? fmaf(ab1.x, mx1, ab1.y) : fmaf(ab1.x, mn1, ab1.y);
  unsigned o = (unsigned)f2bf(fmaxf(t0, 0.f)) |
               ((unsigned)f2bf(fmaxf(t1, 0.f)) << 16);
  h2[n * 32 + wd] = o;
}

// ---------------------------------------------------------------------------
// MFMA gathered conv, barrier-free / array-free, 32-node waves.
// Each wave: 32 nodes (two 16-node groups x/y sharing one B stream) x 64
// cols. B read direct from global (L2-resident), prefetched 1 tap ahead into
// named regs; B traffic per node HALVED vs 16-node waves; 16 MFMA/tap/wave.
// Neighbor indices in a block-staged LDS table, read inline with literal
// offsets (no per-lane idx registers). All pipeline state = named scalars.
// ---------------------------------------------------------------------------
template <int OUTC>
__global__ __launch_bounds__(OUTC * 2) void k_mconv(
    const unsigned short* __restrict__ src, const int* __restrict__ neigh,
    const unsigned short* __restrict__ Wf, float* __restrict__ out,
    float* __restrict__ stats, int M) {
  constexpr int CG = OUTC / 64;      // col groups (2 or 1)
  constexpr int THREADS = OUTC * 2;  // 256 or 128
  constexpr int PT = CG * 512;       // uint4 per tap
  constexpr int K1 = 4 * CG;         // ks1=1 fragment offset (frags)
  __shared__ int nlds[64 * 27];

  const int tid = threadIdx.x;
  const int lane = tid & 63;
  const int w = tid >> 6;
  const int ng = w & 1, cg = w >> 1;   // cg==0 when OUTC==64
  const int l15 = lane & 15, lq = lane >> 4;
  const uint4* WfU = (const uint4*)Wf;
  const int cg4 = cg * 4;
  const int offA = (ng * 32 + l15) * 27;  // LDS idx offsets (literal +k reads)
  const int offB = offA + 16 * 27;

  // stage all 64 nodes' neighbor indices (coalesced)
  for (int e = tid; e < 64 * 27; e += THREADS) {
    int row = blockIdx.x * 64 + e / 27;
    nlds[e] = (row < M) ? neigh[row * 27 + e % 27] : -1;
  }

  FragU x0l, x0h, x1l, x1h, x2l, x2h;  // group A frags, 3-slot rotation
  FragU y0l, y0h, y1l, y1h, y2l, y2h;  // group B frags
  FragU qa0, qa1, qa2, qa3, qa4, qa5, qa6, qa7;  // B dbuf
  FragU qb0, qb1, qb2, qb3, qb4, qb5, qb6, qb7;
  f32x4 ca0 = {0.f, 0.f, 0.f, 0.f}, ca1 = {0.f, 0.f, 0.f, 0.f};
  f32x4 ca2 = {0.f, 0.f, 0.f, 0.f}, ca3 = {0.f, 0.f, 0.f, 0.f};
  f32x4 cb0 = {0.f, 0.f, 0.f, 0.f}, cb1 = {0.f, 0.f, 0.f, 0.f};
  f32x4 cb2 = {0.f, 0.f, 0.f, 0.f}, cb3 = {0.f, 0.f, 0.f, 0.f};

#define LDB(QP, k)                                                         \
  {                                                                        \
    const uint4* bp_ = WfU + ((k)*PT + cg4 * 64 + lane);                   \
    (QP##0).u = bp_[0];                                                    \
    (QP##1).u = bp_[64];                                                   \
    (QP##2).u = bp_[128];                                                  \
    (QP##3).u = bp_[192];                                                  \
    (QP##4).u = bp_[K1 * 64];                                              \
    (QP##5).u = bp_[K1 * 64 + 64];                                         \
    (QP##6).u = bp_[K1 * 64 + 128];                                        \
    (QP##7).u = bp_[K1 * 64 + 192];                                        \
  }

#define GATH2(AL, AH, ix)                                                  \
  {                                                                        \
    int ix_ = (ix);                                                        \
    if (ix_ >= 0) {                                                        \
      const char* bp_ = (const char*)src + (size_t)ix_ * 128 + lq * 16;    \
      AL.u = *(const uint4*)bp_;                                           \
      AH.u = *(const uint4*)(bp_ + 64);                                    \
    } else {                                                               \
      AL.u = uint4{0u, 0u, 0u, 0u};                                        \
      AH.u = uint4{0u, 0u, 0u, 0u};                                        \
    }                                                                      \
  }

// per-acc order: (l, Qlow) then (h, Qhigh) — identical numerics to r10;
// chains interleaved c0..c3 so dependent MFMAs are 4 apart.
#define MMG(AL, AH, C0, C1, C2, C3, QP)                                       \
  C0 = __builtin_amdgcn_mfma_f32_16x16x32_bf16((AL).b, (QP##0).b, C0, 0, 0, 0); \
  C1 = __builtin_amdgcn_mfma_f32_16x16x32_bf16((AL).b, (QP##1).b, C1, 0, 0, 0); \
  C2 = __builtin_amdgcn_mfma_f32_16x16x32_bf16((AL).b, (QP##2).b, C2, 0, 0, 0); \
  C3 = __builtin_amdgcn_mfma_f32_16x16x32_bf16((AL).b, (QP##3).b, C3, 0, 0, 0); \
  C0 = __builtin_amdgcn_mfma_f32_16x16x32_bf16((AH).b, (QP##4).b, C0, 0, 0, 0); \
  C1 = __builtin_amdgcn_mfma_f32_16x16x32_bf16((AH).b, (QP##5).b, C1, 0, 0, 0); \
  C2 = __builtin_amdgcn_mfma_f32_16x16x32_bf16((AH).b, (QP##6).b, C2, 0, 0, 0); \
  C3 = __builtin_amdgcn_mfma_f32_16x16x32_bf16((AH).b, (QP##7).b, C3, 0, 0, 0);

// TAP(k): prefetch B tap k+1 -> QN; MFMA tap k (both groups, shared QP);
// gather tap k+3 into freed slots (idx read inline from LDS, literal k+3).
#define TAP(k, XL, XH, YL, YH, QP, QN)                 \
  {                                                    \
    if ((k) + 1 < 27) LDB(QN, (k) + 1)                 \
    MMG(XL, XH, ca0, ca1, ca2, ca3, QP)                \
    MMG(YL, YH, cb0, cb1, cb2, cb3, QP)                \
    if ((k) + 3 < 27) {                                \
      GATH2(XL, XH, nlds[offA + (k) + 3])              \
      GATH2(YL, YH, nlds[offB + (k) + 3])              \
    }                                                  \
  }

  // B tap 0 issued before the barrier (rides across it)
  LDB(qa, 0)
  sync_lds();  // nlds visible

  // prologue gathers: taps 0..2, both groups (12 uint4 in flight)
  GATH2(x0l, x0h, nlds[offA + 0])
  GATH2(y0l, y0h, nlds[offB + 0])
  GATH2(x1l, x1h, nlds[offA + 1])
  GATH2(y1l, y1h, nlds[offB + 1])
  GATH2(x2l, x2h, nlds[offA + 2])
  GATH2(y2l, y2h, nlds[offB + 2])

  TAP(0, x0l, x0h, y0l, y0h, qa, qb)
  TAP(1, x1l, x1h, y1l, y1h, qb, qa)
  TAP(2, x2l, x2h, y2l, y2h, qa, qb)
  TAP(3, x0l, x0h, y0l, y0h, qb, qa)
  TAP(4, x1l, x1h, y1l, y1h, qa, qb)
  TAP(5, x2l, x2h, y2l, y2h, qb, qa)
  TAP(6, x0l, x0h, y0l, y0h, qa, qb)
  TAP(7, x1l, x1h, y1l, y1h, qb, qa)
  TAP(8, x2l, x2h, y2l, y2h, qa, qb)
  TAP(9, x0l, x0h, y0l, y0h, qb, qa)
  TAP(10, x1l, x1h, y1l, y1h, qa, qb)
  TAP(11, x2l, x2h, y2l, y2h, qb, qa)
  TAP(12, x0l, x0h, y0l, y0h, qa, qb)
  TAP(13, x1l, x1h, y1l, y1h, qb, qa)
  TAP(14, x2l, x2h, y2l, y2h, qa, qb)
  TAP(15, x0l, x0h, y0l, y0h, qb, qa)
  TAP(16, x1l, x1h, y1l, y1h, qa, qb)
  TAP(17, x2l, x2h, y2l, y2h, qb, qa)
  TAP(18, x0l, x0h, y0l, y0h, qa, qb)
  TAP(19, x1l, x1h, y1l, y1h, qb, qa)
  TAP(20, x2l, x2h, y2l, y2h, qa, qb)
  TAP(21, x0l, x0h, y0l, y0h, qb, qa)
  TAP(22, x1l, x1h, y1l, y1h, qa, qb)
  TAP(23, x2l, x2h, y2l, y2h, qb, qa)
  TAP(24, x0l, x0h, y0l, y0h, qa, qb)
  TAP(25, x1l, x1h, y1l, y1h, qb, qa)
  TAP(26, x2l, x2h, y2l, y2h, qa, qb)
#undef TAP
#undef MMG
#undef GATH2
#undef LDB

  // store (C/D: col=lane&15, row=(lane>>4)*4+r); group x rows, then +16
  const int rbA = blockIdx.x * 64 + ng * 32 + lq * 4;
#pragma unroll
  for (int nf = 0; nf < 4; ++nf) {
    f32x4 a = (nf == 0) ? ca0 : (nf == 1) ? ca1 : (nf == 2) ? ca2 : ca3;
    f32x4 b = (nf == 0) ? cb0 : (nf == 1) ? cb1 : (nf == 2) ? cb2 : cb3;
    int c = cg * 64 + nf * 16 + l15;
#pragma unroll
    for (int r = 0; r < 4; ++r) {
      int rowA = rbA + r, rowB = rbA + 16 + r;
      if (rowA < M) out[rowA * OUTC + c] = a[r];
      if (rowB < M) out[rowB * OUTC + c] = b[r];
    }
  }

  // stats (invalid rows contributed zeros); sum both groups
#pragma unroll
  for (int nf = 0; nf < 4; ++nf) {
    f32x4 a = (nf == 0) ? ca0 : (nf == 1) ? ca1 : (nf == 2) ? ca2 : ca3;
    f32x4 b = (nf == 0) ? cb0 : (nf == 1) ? cb1 : (nf == 2) ? cb2 : cb3;
    float s = 0.f, q = 0.f;
#pragma unroll
    for (int r = 0; r < 4; ++r) {
      s += a[r] + b[r];
      q += a[r] * a[r] + b[r] * b[r];
    }
    s += __shfl_xor(s, 16); s += __shfl_xor(s, 32);
    q += __shfl_xor(q, 16); q += __shfl_xor(q, 32);
    if (lane < 16) {
      int c = cg * 64 + nf * 16 + lane;
      atomicAdd(&stats[c], s);
      atomicAdd(&stats[OUTC + c], q);
    }
  }
}

// ---------------------------------------------------------------------------
// BN+ReLU on y2d channels 0..63 -> out1 (bf16)
// ---------------------------------------------------------------------------
__global__ __launch_bounds__(256) void k_bnrelu(
    const float* __restrict__ y2d, const float* __restrict__ stats,
    const float* __restrict__ gamma, const float* __restrict__ beta,
    unsigned short* __restrict__ out1) {
  int e = blockIdx.x * 256 + threadIdx.x;
  int i = e >> 6, c = e & 63;
  float2 ab = bn_ab(stats[c], stats[128 + c], 1.0f / CN3, gamma[c], beta[c]);
  out1[e] = f2bf(fmaxf(fmaf(ab.x, y2d[i * 128 + c], ab.y), 0.f));
}

// ---------------------------------------------------------------------------
// Final: relu(BN2(y3) + BNd(y2d[:,64:128]))
// ---------------------------------------------------------------------------
__global__ __launch_bounds__(256) void k_final(
    const float* __restrict__ y3, const float* __restrict__ y2d,
    const float* __restrict__ stats2, const float* __restrict__ stats1d,
    const float* __restrict__ g2, const float* __restrict__ b2,
    const float* __restrict__ gd, const float* __restrict__ bd,
    float* __restrict__ dout) {
  int e = blockIdx.x * 256 + threadIdx.x;
  int i = e >> 6, c = e & 63;
  float2 ab2 = bn_ab(stats2[c], stats2[64 + c], 1.0f / CN3, g2[c], b2[c]);
  float2 abd =
      bn_ab(stats1d[64 + c], stats1d[192 + c], 1.0f / CN3, gd[c], bd[c]);
  float o = fmaf(ab2.x, y3[e], ab2.y) + fmaf(abd.x, y2d[i * 128 + 64 + c], abd.y);
  dout[e] = fmaxf(o, 0.f);
}

// ---------------------------------------------------------------------------
extern "C" void kernel_launch(void* const* d_in, const int* in_sizes, int n_in,
                              void* d_out, int out_size, void* d_ws,
                              size_t ws_size, hipStream_t stream) {
  const float* x = (const float*)d_in[0];
  const int* neigh_stem = (const int*)d_in[1];
  const int* pool_child = (const int*)d_in[2];
  const int* neigh_ds = (const int*)d_in[3];
  const int* neigh_res = (const int*)d_in[4];
  const float* W_stem = (const float*)d_in[5];
  const float* g_stem = (const float*)d_in[6];
  const float* b_stem = (const float*)d_in[7];
  const float* W1 = (const float*)d_in[8];
  const float* g1 = (const float*)d_in[9];
  const float* b1 = (const float*)d_in[10];
  const float* W2 = (const float*)d_in[11];
  const float* g2 = (const float*)d_in[12];
  const float* b2 = (const float*)d_in[13];
  const float* Wd = (const float*)d_in[14];
  const float* gd = (const float*)d_in[15];
  const float* bd = (const float*)d_in[16];
  float* out = (float*)d_out;
  float* ws = (float*)d_ws;

  // Workspace layout (float units):
  unsigned short* y1bf = (unsigned short*)ws;              // N1*64 bf16 (9.6M f)
  float* y2d = ws;                                         // N3*128 f32 (reuse)
  unsigned short* out1bf = (unsigned short*)(ws + 3840000);// N3*64 bf16
  float* y3 = ws + 4800000;                                // N3*64 f32
  unsigned short* h2bf = (unsigned short*)(ws + 9600000);  // N2*64 bf16 (2.56M f)
  unsigned int* xbf = (unsigned int*)(ws + 12160000);      // N0*4 bf16 (2M f)
  unsigned short* Wst = (unsigned short*)(ws + 14160000);  // 8192 bf16
  unsigned short* Wdual = (unsigned short*)(ws + 14164096);// 221184 bf16
  unsigned short* Wres = (unsigned short*)(ws + 14274688); // 110592 bf16
  float* stats = ws + 14329984;                            // 512 f32
  float* stats_stem = stats;                               // [128]
  float* stats_1d = stats + 128;                           // [256]
  float* stats_2 = stats + 384;                            // [128]

  hipMemsetAsync(stats, 0, 512 * sizeof(float), stream);

  k_prep_x<<<(CN0 + 255) / 256, 256, 0, stream>>>(x, xbf);
  k_prep_stem<<<(8192 + 255) / 256, 256, 0, stream>>>(W_stem, Wst);
  k_prep_dual<<<(27 * 8192 + 255) / 256, 256, 0, stream>>>(W1, Wd, Wdual);
  k_prep_res<<<(27 * 4096 + 255) / 256, 256, 0, stream>>>(W2, Wres);

  // 4688 tiles of 64 nodes = 4 tiles x 1172 blocks
  k_stem_mfma<<<1172, 256, 0, stream>>>(
      (const unsigned short*)xbf, neigh_stem, Wst, y1bf, stats_stem);
  k_pool<<<CN2 / 8, 256, 0, stream>>>((const unsigned int*)y1bf, pool_child,
                                      stats_stem, g_stem, b_stem,
                                      (unsigned int*)h2bf);
  // 469 blocks of 64 nodes
  k_mconv<128><<<(CN3 + 63) / 64, 256, 0, stream>>>(h2bf, neigh_ds, Wdual,
                                                    y2d, stats_1d, CN3);
  k_bnrelu<<<CN3 * 64 / 256, 256, 0, stream>>>(y2d, stats_1d, g1, b1, out1bf);
  k_mconv<64><<<(CN3 + 63) / 64, 128, 0, stream>>>(out1bf, neigh_res, Wres,
                                                   y3, stats_2, CN3);
  k_final<<<CN3 * 64 / 256, 256, 0, stream>>>(y3, y2d, stats_2, stats_1d, g2,
                                              b2, gd, bd, out);
}